// Round 1
// baseline (378.500 us; speedup 1.0000x reference)
//
#include <hip/hip_runtime.h>
#include <hip/hip_bf16.h>

#define Nn 10000
#define Ee 160000
#define Fin 128
#define Hid 256
#define Cc 64

// ---------------- init: zero accumulators, deg=1 (self loop), counts=0 ----------
__global__ __launch_bounds__(256) void init_kernel(float* deg, float* degrow, int* cnt,
                                                   int* cursor, float* acc) {
    int i = blockIdx.x * 256 + threadIdx.x;
    if (i < Nn) { deg[i] = 1.0f; degrow[i] = 0.0f; cnt[i] = 0; cursor[i] = 0; }
    if (blockIdx.x == 0 && threadIdx.x < 132) acc[threadIdx.x] = 0.0f;
}

// ---------------- detect int64 vs int32 storage of edge_index -------------------
// int64 little-endian with values < 2^31  => every odd 32-bit word is 0.
__global__ void detect_kernel(const int* w, int* flag) {
    __shared__ int any;
    if (threadIdx.x == 0) any = 0;
    __syncthreads();
    for (int j = threadIdx.x; j < 1024; j += 256) {
        if (w[2 * j + 1] != 0) atomicOr(&any, 1);
    }
    __syncthreads();
    if (threadIdx.x == 0) *flag = (any == 0) ? 1 : 0;   // 1 => int64 layout
}

__global__ __launch_bounds__(256) void convert_kernel(const void* ei, const int* flag,
                                                      int* out, int n2e) {
    int i = blockIdx.x * 256 + threadIdx.x;
    if (i >= n2e) return;
    if (*flag) out[i] = (int)((const long long*)ei)[i];
    else       out[i] = ((const int*)ei)[i];
}

// ---------------- edge stats: weighted in-degree, adj row sums, CSC counts ------
__global__ __launch_bounds__(256) void edge_stats_kernel(const int* __restrict__ row,
                                                         const int* __restrict__ col,
                                                         const float* __restrict__ ew,
                                                         float* deg, float* degrow, int* cnt,
                                                         float* g_sum_ea, int E) {
    int e = blockIdx.x * 256 + threadIdx.x;
    float v = 0.0f;
    if (e < E) {
        int r = row[e], c = col[e];
        float w = ew[e];
        v = w;
        atomicAdd(&deg[c], w);
        atomicAdd(&degrow[r], w);
        atomicAdd(&cnt[c], 1);
    }
    for (int off = 32; off; off >>= 1) v += __shfl_xor(v, off);
    __shared__ float sred[4];
    if ((threadIdx.x & 63) == 0) sred[threadIdx.x >> 6] = v;
    __syncthreads();
    if (threadIdx.x == 0) atomicAdd(g_sum_ea, sred[0] + sred[1] + sred[2] + sred[3]);
}

__global__ __launch_bounds__(256) void dinv_kernel(const float* deg, float* dinv) {
    int i = blockIdx.x * 256 + threadIdx.x;
    if (i < Nn) dinv[i] = rsqrtf(deg[i]);
}

// ---------------- single-block exclusive scan (offsets) -------------------------
__global__ __launch_bounds__(1024) void scan_kernel(const int* cnt, int* offs, int n) {
    __shared__ int sh[1024];
    __shared__ int carry;
    if (threadIdx.x == 0) { carry = 0; offs[0] = 0; }
    __syncthreads();
    for (int base = 0; base < n; base += 1024) {
        int i = base + (int)threadIdx.x;
        int v = (i < n) ? cnt[i] : 0;
        sh[threadIdx.x] = v;
        __syncthreads();
        for (int d = 1; d < 1024; d <<= 1) {
            int t2 = 0;
            if (threadIdx.x >= (unsigned)d) t2 = sh[threadIdx.x - d];
            __syncthreads();
            if (threadIdx.x >= (unsigned)d) sh[threadIdx.x] += t2;
            __syncthreads();
        }
        if (i < n) offs[i + 1] = carry + sh[threadIdx.x];
        __syncthreads();
        if (threadIdx.x == 0) carry += sh[1023];
        __syncthreads();
    }
}

// ---------------- fill CSC with (row, norm) -------------------------------------
__global__ __launch_bounds__(256) void fill_kernel(const int* __restrict__ row,
                                                   const int* __restrict__ col,
                                                   const float* __restrict__ ew,
                                                   const float* __restrict__ dinv,
                                                   const int* __restrict__ offs, int* cursor,
                                                   int* cscr, float* cscw, int E) {
    int e = blockIdx.x * 256 + threadIdx.x;
    if (e >= E) return;
    int r = row[e], c = col[e];
    int slot = offs[c] + atomicAdd(&cursor[c], 1);
    cscr[slot] = r;
    cscw[slot] = dinv[r] * ew[e] * dinv[c];
}

// ---------------- fp32 tiled GEMM: C[M,NC] = A[M,K] @ W[K,NC] -------------------
#define BM 64
#define BN 64
#define BK 16
__global__ __launch_bounds__(256) void gemm_kernel(const float* __restrict__ A,
                                                   const float* __restrict__ W,
                                                   float* __restrict__ Cmat,
                                                   int M, int K, int NC) {
    __shared__ float As[BK][BM];
    __shared__ float Bs[BK][BN];
    int t = threadIdx.x;
    int m0 = blockIdx.x * BM;
    int n0 = blockIdx.y * BN;
    int ty = t >> 4;            // 0..15
    int tx = t & 15;            // 0..15
    int lar = t >> 2;           // 0..63  (A row in tile)
    int lak = (t & 3) * 4;      // 0,4,8,12
    int lbk = t >> 4;           // 0..15  (B k in tile)
    int lbn = (t & 15) * 4;
    float acc[4][4] = {{0.f}};
    for (int k0 = 0; k0 < K; k0 += BK) {
        float4 av = make_float4(0.f, 0.f, 0.f, 0.f);
        int arow = m0 + lar;
        if (arow < M) av = *(const float4*)(A + (size_t)arow * K + k0 + lak);
        As[lak + 0][lar] = av.x;
        As[lak + 1][lar] = av.y;
        As[lak + 2][lar] = av.z;
        As[lak + 3][lar] = av.w;
        *(float4*)&Bs[lbk][lbn] = *(const float4*)(W + (size_t)(k0 + lbk) * NC + n0 + lbn);
        __syncthreads();
#pragma unroll
        for (int kk = 0; kk < BK; kk++) {
            float4 a4 = *(const float4*)&As[kk][ty << 2];
            float4 b4 = *(const float4*)&Bs[kk][tx << 2];
            float ar[4] = {a4.x, a4.y, a4.z, a4.w};
            float br[4] = {b4.x, b4.y, b4.z, b4.w};
#pragma unroll
            for (int r = 0; r < 4; r++)
#pragma unroll
                for (int c = 0; c < 4; c++)
                    acc[r][c] = fmaf(ar[r], br[c], acc[r][c]);
        }
        __syncthreads();
    }
#pragma unroll
    for (int r = 0; r < 4; r++) {
        int rowi = m0 + (ty << 2) + r;
        if (rowi < M)
            *(float4*)(Cmat + (size_t)rowi * NC + n0 + (tx << 2)) =
                make_float4(acc[r][0], acc[r][1], acc[r][2], acc[r][3]);
    }
}

// ---------------- GCN aggregation: out = relu(D^-1/2 A D^-1/2 tmp + b) ----------
__global__ __launch_bounds__(256) void agg_kernel(const float* __restrict__ tmp,
                                                  const float* __restrict__ dinv,
                                                  const int* __restrict__ offs,
                                                  const int* __restrict__ cscr,
                                                  const float* __restrict__ cscw,
                                                  const float* __restrict__ bias,
                                                  float* __restrict__ outh) {
    int i = blockIdx.x;
    int f = threadIdx.x;
    float di = dinv[i];
    float a = di * di * tmp[(size_t)i * Hid + f];     // self loop: norm = dinv^2
    int e0 = offs[i], e1 = offs[i + 1];
    for (int k = e0; k < e1; k++) {
        int r = cscr[k];
        float w = cscw[k];
        a = fmaf(w, tmp[(size_t)r * Hid + f], a);
    }
    outh[(size_t)i * Hid + f] = fmaxf(a + bias[f], 0.0f);
}

// ---------------- fused GEMM3 + softmax + cluster/ca partials -------------------
__global__ __launch_bounds__(256) void softmax_kernel(const float* __restrict__ h2,
                                                      const float* __restrict__ Wm,
                                                      const float* __restrict__ bm,
                                                      const float* __restrict__ degrow,
                                                      float* __restrict__ s_out,
                                                      float* __restrict__ g_clsz,
                                                      float* __restrict__ g_ca) {
    __shared__ float sh[16 * Hid];
    __shared__ float redc[4][Cc];
    __shared__ float reda[4][Cc];
    int t = threadIdx.x;
    int rb = blockIdx.x * 16;
    const float4* src = (const float4*)(h2 + (size_t)rb * Hid);
    float4* dst = (float4*)sh;
    for (int j = t; j < 16 * Hid / 4; j += 256) dst[j] = src[j];
    __syncthreads();
    int wave = t >> 6, f = t & 63;
    float a0 = bm[f], a1 = a0, a2 = a0, a3 = a0;
    const float* hrow = &sh[(wave * 4) * Hid];
#pragma unroll 4
    for (int k = 0; k < Hid; k++) {
        float w = Wm[k * Cc + f];
        a0 = fmaf(hrow[k], w, a0);
        a1 = fmaf(hrow[Hid + k], w, a1);
        a2 = fmaf(hrow[2 * Hid + k], w, a2);
        a3 = fmaf(hrow[3 * Hid + k], w, a3);
    }
    float av[4] = {a0, a1, a2, a3};
    float pc = 0.0f, pa = 0.0f;
#pragma unroll
    for (int r = 0; r < 4; r++) {
        int rowi = rb + wave * 4 + r;
        float v = av[r];
        float mx = v;
        for (int o = 32; o; o >>= 1) mx = fmaxf(mx, __shfl_xor(mx, o));
        float e = __expf(v - mx);
        float ssum = e;
        for (int o = 32; o; o >>= 1) ssum += __shfl_xor(ssum, o);
        float sv = e / ssum;
        s_out[(size_t)rowi * Cc + f] = sv;
        pc += sv;
        pa += sv * degrow[rowi];
    }
    redc[wave][f] = pc;
    reda[wave][f] = pa;
    __syncthreads();
    if (wave == 0) {
        float c = redc[0][f] + redc[1][f] + redc[2][f] + redc[3][f];
        float a = reda[0][f] + reda[1][f] + reda[2][f] + reda[3][f];
        atomicAdd(&g_clsz[f], c);
        atomicAdd(&g_ca[f], a);
    }
}

// ---------------- trace_out_adj = sum_e ea * dot(s[row], s[col]) ----------------
__global__ __launch_bounds__(256) void trace_kernel(const int* __restrict__ row,
                                                    const int* __restrict__ col,
                                                    const float* __restrict__ ea,
                                                    const float* __restrict__ s,
                                                    float* g_trace, int E) {
    int lane = threadIdx.x & 63;
    int wid = (blockIdx.x * 256 + threadIdx.x) >> 6;
    int nw = (gridDim.x * 256) >> 6;
    float a = 0.0f;
    for (int e = wid; e < E; e += nw) {
        int r = row[e], c = col[e];
        a = fmaf(ea[e], s[(size_t)r * Cc + lane] * s[(size_t)c * Cc + lane], a);
    }
    for (int o = 32; o; o >>= 1) a += __shfl_xor(a, o);
    if (lane == 0) atomicAdd(g_trace, a);
}

// ---------------- final scalars -------------------------------------------------
__global__ void final_kernel(const float* acc, float* out_tail) {
    // acc: [0..63]=cluster_size, [64..127]=ca, [128]=sum_ea, [129]=trace
    float m = acc[128] * 0.5f;
    float caca = 0.0f, cc = 0.0f;
    for (int k = 0; k < Cc; k++) {
        caca += acc[64 + k] * acc[64 + k];
        cc += acc[k] * acc[k];
    }
    float tn = caca / (2.0f * m);
    float spec = -(acc[129] - tn) / (2.0f * m);
    float clust = sqrtf(cc) / (float)Nn * 8.0f - 1.0f;   // sqrt(C)=8
    out_tail[0] = 100.0f * (spec + clust);
    out_tail[1] = 100.0f * spec;
    out_tail[2] = 100.0f * clust;
}

extern "C" void kernel_launch(void* const* d_in, const int* in_sizes, int n_in,
                              void* d_out, int out_size, void* d_ws, size_t ws_size,
                              hipStream_t stream) {
    const float* x  = (const float*)d_in[0];
    const float* ea = (const float*)d_in[1];
    const float* W1 = (const float*)d_in[2];
    const float* b1 = (const float*)d_in[3];
    const float* W2 = (const float*)d_in[4];
    const float* b2 = (const float*)d_in[5];
    const float* Wm = (const float*)d_in[6];
    const float* bm = (const float*)d_in[7];
    const void*  ei = d_in[8];
    float* out = (float*)d_out;

    size_t off = 0;
    auto carve = [&](size_t bytes) -> void* {
        void* p = (char*)d_ws + off;
        off += (bytes + 255) & ~(size_t)255;
        return p;
    };
    float* acc    = (float*)carve(132 * 4);
    int*   flag   = (int*)carve(4);
    float* deg    = (float*)carve(Nn * 4);
    float* dinv   = (float*)carve(Nn * 4);
    float* degrow = (float*)carve(Nn * 4);
    int*   cnt    = (int*)carve(Nn * 4);
    int*   offs   = (int*)carve((Nn + 1) * 4);
    int*   cursor = (int*)carve(Nn * 4);
    int*   ebuf   = (int*)carve((size_t)2 * Ee * 4);   // row32 | col32 contiguous
    int*   cscr   = (int*)carve(Ee * 4);
    float* cscw   = (float*)carve(Ee * 4);
    float* bufA   = (float*)carve((size_t)Nn * Hid * 4);
    float* bufB   = (float*)carve((size_t)Nn * Hid * 4);
    int* row32 = ebuf;
    int* col32 = ebuf + Ee;

    init_kernel<<<(Nn + 255) / 256, 256, 0, stream>>>(deg, degrow, cnt, cursor, acc);
    detect_kernel<<<1, 256, 0, stream>>>((const int*)ei, flag);
    convert_kernel<<<(2 * Ee + 255) / 256, 256, 0, stream>>>(ei, flag, ebuf, 2 * Ee);
    edge_stats_kernel<<<(Ee + 255) / 256, 256, 0, stream>>>(row32, col32, ea, deg, degrow,
                                                            cnt, acc + 128, Ee);
    dinv_kernel<<<(Nn + 255) / 256, 256, 0, stream>>>(deg, dinv);
    scan_kernel<<<1, 1024, 0, stream>>>(cnt, offs, Nn);
    fill_kernel<<<(Ee + 255) / 256, 256, 0, stream>>>(row32, col32, ea, dinv, offs, cursor,
                                                      cscr, cscw, Ee);
    dim3 ggrid((Nn + BM - 1) / BM, Hid / BN);
    gemm_kernel<<<ggrid, 256, 0, stream>>>(x, W1, bufA, Nn, Fin, Hid);
    agg_kernel<<<Nn, 256, 0, stream>>>(bufA, dinv, offs, cscr, cscw, b1, bufB);
    gemm_kernel<<<ggrid, 256, 0, stream>>>(bufB, W2, bufA, Nn, Hid, Hid);
    agg_kernel<<<Nn, 256, 0, stream>>>(bufA, dinv, offs, cscr, cscw, b2, bufB);
    softmax_kernel<<<Nn / 16, 256, 0, stream>>>(bufB, Wm, bm, degrow, out, acc, acc + 64);
    trace_kernel<<<256, 256, 0, stream>>>(row32, col32, ea, out, acc + 129, Ee);
    final_kernel<<<1, 1, 0, stream>>>(acc, out + (size_t)Nn * Cc);
}

// Round 2
// 310.466 us; speedup vs baseline: 1.2191x; 1.2191x over previous
//
#include <hip/hip_runtime.h>
#include <hip/hip_bf16.h>

#define Nn 10000
#define Ee 160000
#define Fin 128
#define Hid 256
#define Cc 64

// ---------------- init: zero accumulators, deg=1 (self loop), counts=0 ----------
__global__ __launch_bounds__(256) void init_kernel(float* deg, float* degrow, int* cnt,
                                                   int* cursor, float* acc) {
    int i = blockIdx.x * 256 + threadIdx.x;
    if (i < Nn) { deg[i] = 1.0f; degrow[i] = 0.0f; cnt[i] = 0; cursor[i] = 0; }
    if (blockIdx.x == 0 && threadIdx.x < 132) acc[threadIdx.x] = 0.0f;
}

// ---------------- detect int64 vs int32 storage of edge_index -------------------
__global__ void detect_kernel(const int* w, int* flag) {
    __shared__ int any;
    if (threadIdx.x == 0) any = 0;
    __syncthreads();
    for (int j = threadIdx.x; j < 1024; j += 256) {
        if (w[2 * j + 1] != 0) atomicOr(&any, 1);
    }
    __syncthreads();
    if (threadIdx.x == 0) *flag = (any == 0) ? 1 : 0;   // 1 => int64 layout
}

__global__ __launch_bounds__(256) void convert_kernel(const void* ei, const int* flag,
                                                      int* out, int n2e) {
    int i = blockIdx.x * 256 + threadIdx.x;
    if (i >= n2e) return;
    if (*flag) out[i] = (int)((const long long*)ei)[i];
    else       out[i] = ((const int*)ei)[i];
}

// ---------------- edge stats: weighted in-degree, adj row sums, CSC counts ------
__global__ __launch_bounds__(256) void edge_stats_kernel(const int* __restrict__ row,
                                                         const int* __restrict__ col,
                                                         const float* __restrict__ ew,
                                                         float* deg, float* degrow, int* cnt,
                                                         float* g_sum_ea, int E) {
    int e = blockIdx.x * 256 + threadIdx.x;
    float v = 0.0f;
    if (e < E) {
        int r = row[e], c = col[e];
        float w = ew[e];
        v = w;
        atomicAdd(&deg[c], w);
        atomicAdd(&degrow[r], w);
        atomicAdd(&cnt[c], 1);
    }
    for (int off = 32; off; off >>= 1) v += __shfl_xor(v, off);
    __shared__ float sred[4];
    if ((threadIdx.x & 63) == 0) sred[threadIdx.x >> 6] = v;
    __syncthreads();
    if (threadIdx.x == 0) atomicAdd(g_sum_ea, sred[0] + sred[1] + sred[2] + sred[3]);
}

__global__ __launch_bounds__(256) void dinv_kernel(const float* deg, float* dinv) {
    int i = blockIdx.x * 256 + threadIdx.x;
    if (i < Nn) dinv[i] = rsqrtf(deg[i]);
}

// ---------------- single-block exclusive scan via wave shuffles -----------------
__global__ __launch_bounds__(1024) void scan_kernel(const int* cnt, int* offs, int n) {
    __shared__ int wsum[16];
    __shared__ int carry;
    int lane = threadIdx.x & 63;
    int w = threadIdx.x >> 6;
    if (threadIdx.x == 0) { carry = 0; offs[0] = 0; }
    __syncthreads();
    for (int base = 0; base < n; base += 1024) {
        int i = base + (int)threadIdx.x;
        int v = (i < n) ? cnt[i] : 0;
        int s = v;
        for (int d = 1; d < 64; d <<= 1) {
            int t = __shfl_up(s, d);
            if (lane >= d) s += t;
        }
        if (lane == 63) wsum[w] = s;
        __syncthreads();
        if (w == 0 && lane < 16) {
            int ws = wsum[lane];
            for (int d = 1; d < 16; d <<= 1) {
                int t = __shfl_up(ws, d);
                if (lane >= d) ws += t;
            }
            wsum[lane] = ws;
        }
        __syncthreads();
        int wofs = (w > 0) ? wsum[w - 1] : 0;
        int total = wsum[15];
        if (i < n) offs[i + 1] = carry + wofs + s;
        __syncthreads();
        if (threadIdx.x == 0) carry += total;
        __syncthreads();
    }
}

// ---------------- fill CSC with (row, norm) -------------------------------------
__global__ __launch_bounds__(256) void fill_kernel(const int* __restrict__ row,
                                                   const int* __restrict__ col,
                                                   const float* __restrict__ ew,
                                                   const float* __restrict__ dinv,
                                                   const int* __restrict__ offs, int* cursor,
                                                   int* cscr, float* cscw, int E) {
    int e = blockIdx.x * 256 + threadIdx.x;
    if (e >= E) return;
    int r = row[e], c = col[e];
    int slot = offs[c] + atomicAdd(&cursor[c], 1);
    cscr[slot] = r;
    cscw[slot] = dinv[r] * ew[e] * dinv[c];
}

// ---------------- GCN aggregation (no bias/relu): wave per node -----------------
// dst[i] = dinv[i]^2 * src[i] + sum_k w_k * src[r_k]   (agg commutes with @W)
template <int F>
__global__ __launch_bounds__(256) void agg_kernel_t(const float* __restrict__ src,
                                                    const float* __restrict__ dinv,
                                                    const int* __restrict__ offs,
                                                    const int* __restrict__ cscr,
                                                    const float* __restrict__ cscw,
                                                    float* __restrict__ dst) {
    constexpr int VEC = F / 64;                 // floats per lane: 2 (F=128) or 4 (F=256)
    int wave = threadIdx.x >> 6, lane = threadIdx.x & 63;
    int i = blockIdx.x * 4 + wave;
    if (i >= Nn) return;
    float di = dinv[i];
    float acc[VEC];
    const float* rowp = src + (size_t)i * F + lane * VEC;
#pragma unroll
    for (int j = 0; j < VEC; j++) acc[j] = di * di * rowp[j];
    int e0 = offs[i], e1 = offs[i + 1];
    int k = e0;
    for (; k + 1 < e1; k += 2) {
        int r0 = cscr[k], r1 = cscr[k + 1];
        float w0 = cscw[k], w1 = cscw[k + 1];
        const float* p0 = src + (size_t)r0 * F + lane * VEC;
        const float* p1 = src + (size_t)r1 * F + lane * VEC;
        float t0[VEC], t1[VEC];
#pragma unroll
        for (int j = 0; j < VEC; j++) t0[j] = p0[j];
#pragma unroll
        for (int j = 0; j < VEC; j++) t1[j] = p1[j];
#pragma unroll
        for (int j = 0; j < VEC; j++) acc[j] = fmaf(w0, t0[j], acc[j]);
#pragma unroll
        for (int j = 0; j < VEC; j++) acc[j] = fmaf(w1, t1[j], acc[j]);
    }
    if (k < e1) {
        int r0 = cscr[k];
        float w0 = cscw[k];
        const float* p0 = src + (size_t)r0 * F + lane * VEC;
#pragma unroll
        for (int j = 0; j < VEC; j++) acc[j] = fmaf(w0, p0[j], acc[j]);
    }
    float* op = dst + (size_t)i * F + lane * VEC;
#pragma unroll
    for (int j = 0; j < VEC; j++) op[j] = acc[j];
}

// ---------------- fp32 tiled GEMM + fused bias/ReLU epilogue --------------------
#define BM 64
#define BN 64
#define BK 16
__global__ __launch_bounds__(256) void gemm_bias_relu_kernel(const float* __restrict__ A,
                                                             const float* __restrict__ W,
                                                             const float* __restrict__ bias,
                                                             float* __restrict__ Cmat,
                                                             int M, int K, int NC) {
    __shared__ float As[BK][BM];
    __shared__ float Bs[BK][BN];
    int t = threadIdx.x;
    int m0 = blockIdx.x * BM;
    int n0 = blockIdx.y * BN;
    int ty = t >> 4;
    int tx = t & 15;
    int lar = t >> 2;
    int lak = (t & 3) * 4;
    int lbk = t >> 4;
    int lbn = (t & 15) * 4;
    float acc[4][4] = {{0.f}};
    for (int k0 = 0; k0 < K; k0 += BK) {
        float4 av = make_float4(0.f, 0.f, 0.f, 0.f);
        int arow = m0 + lar;
        if (arow < M) av = *(const float4*)(A + (size_t)arow * K + k0 + lak);
        As[lak + 0][lar] = av.x;
        As[lak + 1][lar] = av.y;
        As[lak + 2][lar] = av.z;
        As[lak + 3][lar] = av.w;
        *(float4*)&Bs[lbk][lbn] = *(const float4*)(W + (size_t)(k0 + lbk) * NC + n0 + lbn);
        __syncthreads();
#pragma unroll
        for (int kk = 0; kk < BK; kk++) {
            float4 a4 = *(const float4*)&As[kk][ty << 2];
            float4 b4 = *(const float4*)&Bs[kk][tx << 2];
            float ar[4] = {a4.x, a4.y, a4.z, a4.w};
            float br[4] = {b4.x, b4.y, b4.z, b4.w};
#pragma unroll
            for (int r = 0; r < 4; r++)
#pragma unroll
                for (int c = 0; c < 4; c++)
                    acc[r][c] = fmaf(ar[r], br[c], acc[r][c]);
        }
        __syncthreads();
    }
    float4 b4 = *(const float4*)(bias + n0 + (tx << 2));
    float bb[4] = {b4.x, b4.y, b4.z, b4.w};
#pragma unroll
    for (int r = 0; r < 4; r++) {
        int rowi = m0 + (ty << 2) + r;
        if (rowi < M) {
            float4 o;
            o.x = fmaxf(acc[r][0] + bb[0], 0.0f);
            o.y = fmaxf(acc[r][1] + bb[1], 0.0f);
            o.z = fmaxf(acc[r][2] + bb[2], 0.0f);
            o.w = fmaxf(acc[r][3] + bb[3], 0.0f);
            *(float4*)(Cmat + (size_t)rowi * NC + n0 + (tx << 2)) = o;
        }
    }
}

// ---------------- fused GEMM3 + softmax + cluster/ca partials -------------------
__global__ __launch_bounds__(256) void softmax_kernel(const float* __restrict__ h2,
                                                      const float* __restrict__ Wm,
                                                      const float* __restrict__ bm,
                                                      const float* __restrict__ degrow,
                                                      float* __restrict__ s_out,
                                                      float* __restrict__ g_clsz,
                                                      float* __restrict__ g_ca) {
    __shared__ float sh[16 * Hid];
    __shared__ float redc[4][Cc];
    __shared__ float reda[4][Cc];
    int t = threadIdx.x;
    int rb = blockIdx.x * 16;
    const float4* src = (const float4*)(h2 + (size_t)rb * Hid);
    float4* dst = (float4*)sh;
    for (int j = t; j < 16 * Hid / 4; j += 256) dst[j] = src[j];
    __syncthreads();
    int wave = t >> 6, f = t & 63;
    float a0 = bm[f], a1 = a0, a2 = a0, a3 = a0;
    const float* hrow = &sh[(wave * 4) * Hid];
#pragma unroll 4
    for (int k = 0; k < Hid; k++) {
        float w = Wm[k * Cc + f];
        a0 = fmaf(hrow[k], w, a0);
        a1 = fmaf(hrow[Hid + k], w, a1);
        a2 = fmaf(hrow[2 * Hid + k], w, a2);
        a3 = fmaf(hrow[3 * Hid + k], w, a3);
    }
    float av[4] = {a0, a1, a2, a3};
    float pc = 0.0f, pa = 0.0f;
#pragma unroll
    for (int r = 0; r < 4; r++) {
        int rowi = rb + wave * 4 + r;
        float v = av[r];
        float mx = v;
        for (int o = 32; o; o >>= 1) mx = fmaxf(mx, __shfl_xor(mx, o));
        float e = __expf(v - mx);
        float ssum = e;
        for (int o = 32; o; o >>= 1) ssum += __shfl_xor(ssum, o);
        float sv = e / ssum;
        s_out[(size_t)rowi * Cc + f] = sv;
        pc += sv;
        pa += sv * degrow[rowi];
    }
    redc[wave][f] = pc;
    reda[wave][f] = pa;
    __syncthreads();
    if (wave == 0) {
        float c = redc[0][f] + redc[1][f] + redc[2][f] + redc[3][f];
        float a = reda[0][f] + reda[1][f] + reda[2][f] + reda[3][f];
        atomicAdd(&g_clsz[f], c);
        atomicAdd(&g_ca[f], a);
    }
}

// ---------------- trace_out_adj = sum_e ea * dot(s[row], s[col]) ----------------
// wave per 4-edge chunk, grid-stride: 8 independent gathers in flight.
__global__ __launch_bounds__(256) void trace_kernel(const int* __restrict__ row,
                                                    const int* __restrict__ col,
                                                    const float* __restrict__ ea,
                                                    const float* __restrict__ s,
                                                    float* g_trace, int E) {
    int lane = threadIdx.x & 63;
    int wid = (blockIdx.x * 256 + threadIdx.x) >> 6;
    int nw = (gridDim.x * 256) >> 6;
    float a = 0.0f;
    for (int base = wid * 4; base + 3 < E; base += nw * 4) {
        int r0 = row[base + 0], c0 = col[base + 0];
        int r1 = row[base + 1], c1 = col[base + 1];
        int r2 = row[base + 2], c2 = col[base + 2];
        int r3 = row[base + 3], c3 = col[base + 3];
        float w0 = ea[base + 0], w1 = ea[base + 1];
        float w2 = ea[base + 2], w3 = ea[base + 3];
        float sr0 = s[(size_t)r0 * Cc + lane], sc0 = s[(size_t)c0 * Cc + lane];
        float sr1 = s[(size_t)r1 * Cc + lane], sc1 = s[(size_t)c1 * Cc + lane];
        float sr2 = s[(size_t)r2 * Cc + lane], sc2 = s[(size_t)c2 * Cc + lane];
        float sr3 = s[(size_t)r3 * Cc + lane], sc3 = s[(size_t)c3 * Cc + lane];
        a = fmaf(w0, sr0 * sc0, a);
        a = fmaf(w1, sr1 * sc1, a);
        a = fmaf(w2, sr2 * sc2, a);
        a = fmaf(w3, sr3 * sc3, a);
    }
    for (int o = 32; o; o >>= 1) a += __shfl_xor(a, o);
    if (lane == 0) atomicAdd(g_trace, a);
}

// ---------------- final scalars -------------------------------------------------
__global__ void final_kernel(const float* acc, float* out_tail) {
    float m = acc[128] * 0.5f;
    float caca = 0.0f, cc = 0.0f;
    for (int k = 0; k < Cc; k++) {
        caca += acc[64 + k] * acc[64 + k];
        cc += acc[k] * acc[k];
    }
    float tn = caca / (2.0f * m);
    float spec = -(acc[129] - tn) / (2.0f * m);
    float clust = sqrtf(cc) / (float)Nn * 8.0f - 1.0f;   // sqrt(C)=8
    out_tail[0] = 100.0f * (spec + clust);
    out_tail[1] = 100.0f * spec;
    out_tail[2] = 100.0f * clust;
}

extern "C" void kernel_launch(void* const* d_in, const int* in_sizes, int n_in,
                              void* d_out, int out_size, void* d_ws, size_t ws_size,
                              hipStream_t stream) {
    const float* x  = (const float*)d_in[0];
    const float* ea = (const float*)d_in[1];
    const float* W1 = (const float*)d_in[2];
    const float* b1 = (const float*)d_in[3];
    const float* W2 = (const float*)d_in[4];
    const float* b2 = (const float*)d_in[5];
    const float* Wm = (const float*)d_in[6];
    const float* bm = (const float*)d_in[7];
    const void*  ei = d_in[8];
    float* out = (float*)d_out;

    size_t off = 0;
    auto carve = [&](size_t bytes) -> void* {
        void* p = (char*)d_ws + off;
        off += (bytes + 255) & ~(size_t)255;
        return p;
    };
    float* acc    = (float*)carve(132 * 4);
    int*   flag   = (int*)carve(4);
    float* deg    = (float*)carve(Nn * 4);
    float* dinv   = (float*)carve(Nn * 4);
    float* degrow = (float*)carve(Nn * 4);
    int*   cnt    = (int*)carve(Nn * 4);
    int*   offs   = (int*)carve((Nn + 1) * 4);
    int*   cursor = (int*)carve(Nn * 4);
    int*   ebuf   = (int*)carve((size_t)2 * Ee * 4);
    int*   cscr   = (int*)carve(Ee * 4);
    float* cscw   = (float*)carve(Ee * 4);
    float* bufA   = (float*)carve((size_t)Nn * Hid * 4);
    float* bufB   = (float*)carve((size_t)Nn * Hid * 4);
    int* row32 = ebuf;
    int* col32 = ebuf + Ee;

    init_kernel<<<(Nn + 255) / 256, 256, 0, stream>>>(deg, degrow, cnt, cursor, acc);
    detect_kernel<<<1, 256, 0, stream>>>((const int*)ei, flag);
    convert_kernel<<<(2 * Ee + 255) / 256, 256, 0, stream>>>(ei, flag, ebuf, 2 * Ee);
    edge_stats_kernel<<<(Ee + 255) / 256, 256, 0, stream>>>(row32, col32, ea, deg, degrow,
                                                            cnt, acc + 128, Ee);
    dinv_kernel<<<(Nn + 255) / 256, 256, 0, stream>>>(deg, dinv);
    scan_kernel<<<1, 1024, 0, stream>>>(cnt, offs, Nn);
    fill_kernel<<<(Ee + 255) / 256, 256, 0, stream>>>(row32, col32, ea, dinv, offs, cursor,
                                                      cscr, cscw, Ee);

    // layer 1: xa = agg(x) [F=128], then h1 = relu(xa @ W1 + b1)
    agg_kernel_t<Fin><<<(Nn + 3) / 4, 256, 0, stream>>>(x, dinv, offs, cscr, cscw, bufA);
    dim3 ggrid((Nn + BM - 1) / BM, Hid / BN);
    gemm_bias_relu_kernel<<<ggrid, 256, 0, stream>>>(bufA, W1, b1, bufB, Nn, Fin, Hid);
    // layer 2: h1a = agg(h1) [F=256], then h2 = relu(h1a @ W2 + b2)
    agg_kernel_t<Hid><<<(Nn + 3) / 4, 256, 0, stream>>>(bufB, dinv, offs, cscr, cscw, bufA);
    gemm_bias_relu_kernel<<<ggrid, 256, 0, stream>>>(bufA, W2, b2, bufB, Nn, Hid, Hid);

    softmax_kernel<<<Nn / 16, 256, 0, stream>>>(bufB, Wm, bm, degrow, out, acc, acc + 64);
    trace_kernel<<<1024, 256, 0, stream>>>(row32, col32, ea, out, acc + 129, Ee);
    final_kernel<<<1, 1, 0, stream>>>(acc, out + (size_t)Nn * Cc);
}

// Round 3
// 277.047 us; speedup vs baseline: 1.3662x; 1.1206x over previous
//
#include <hip/hip_runtime.h>
#include <hip/hip_bf16.h>

#define Nn 10000
#define Ee 160000
#define Fin 128
#define Hid 256
#define Cc 64

typedef unsigned int uint32;
typedef unsigned short ushort16;

__device__ inline float2 bfpair(uint32 u) {
    float2 r;
    r.x = __uint_as_float(u << 16);
    r.y = __uint_as_float(u & 0xffff0000u);
    return r;
}
__device__ inline ushort16 f2bf(float f) {
    __hip_bfloat16 h = __float2bfloat16(f);
    union { __hip_bfloat16 h; ushort16 u; } cv;
    cv.h = h;
    return cv.u;
}
__device__ inline uint32 packbf(float a, float b) {
    return (uint32)f2bf(a) | ((uint32)f2bf(b) << 16);
}

// ---------------- init: zero accumulators, deg=1 (self loop), counts=0 ----------
__global__ __launch_bounds__(256) void init_kernel(float* deg, float* degrow, int* cnt,
                                                   int* cursor, float* acc) {
    int i = blockIdx.x * 256 + threadIdx.x;
    if (i < Nn) { deg[i] = 1.0f; degrow[i] = 0.0f; cnt[i] = 0; cursor[i] = 0; }
    if (blockIdx.x == 0 && threadIdx.x < 132) acc[threadIdx.x] = 0.0f;
}

// ---------------- detect int64 vs int32 storage of edge_index -------------------
__global__ void detect_kernel(const int* w, int* flag) {
    __shared__ int any;
    if (threadIdx.x == 0) any = 0;
    __syncthreads();
    for (int j = threadIdx.x; j < 1024; j += 256) {
        if (w[2 * j + 1] != 0) atomicOr(&any, 1);
    }
    __syncthreads();
    if (threadIdx.x == 0) *flag = (any == 0) ? 1 : 0;   // 1 => int64 layout
}

__global__ __launch_bounds__(256) void convert_kernel(const void* ei, const int* flag,
                                                      int* out, int n2e) {
    int i = blockIdx.x * 256 + threadIdx.x;
    if (i >= n2e) return;
    if (*flag) out[i] = (int)((const long long*)ei)[i];
    else       out[i] = ((const int*)ei)[i];
}

// ---------------- x -> bf16 packed ----------------------------------------------
__global__ __launch_bounds__(256) void xbf_kernel(const float* __restrict__ x,
                                                  uint32* __restrict__ xb, int npairs) {
    int i = blockIdx.x * 256 + threadIdx.x;
    if (i >= npairs) return;
    float2 v = *(const float2*)(x + 2 * (size_t)i);
    xb[i] = packbf(v.x, v.y);
}

// ---------------- edge stats: weighted in-degree, adj row sums, CSC counts ------
__global__ __launch_bounds__(256) void edge_stats_kernel(const int* __restrict__ row,
                                                         const int* __restrict__ col,
                                                         const float* __restrict__ ew,
                                                         float* deg, float* degrow, int* cnt,
                                                         float* g_sum_ea, int E) {
    int e = blockIdx.x * 256 + threadIdx.x;
    float v = 0.0f;
    if (e < E) {
        int r = row[e], c = col[e];
        float w = ew[e];
        v = w;
        atomicAdd(&deg[c], w);
        atomicAdd(&degrow[r], w);
        atomicAdd(&cnt[c], 1);
    }
    for (int off = 32; off; off >>= 1) v += __shfl_xor(v, off);
    __shared__ float sred[4];
    if ((threadIdx.x & 63) == 0) sred[threadIdx.x >> 6] = v;
    __syncthreads();
    if (threadIdx.x == 0) atomicAdd(g_sum_ea, sred[0] + sred[1] + sred[2] + sred[3]);
}

__global__ __launch_bounds__(256) void dinv_kernel(const float* deg, float* dinv) {
    int i = blockIdx.x * 256 + threadIdx.x;
    if (i < Nn) dinv[i] = rsqrtf(deg[i]);
}

// ---------------- single-block exclusive scan via wave shuffles -----------------
__global__ __launch_bounds__(1024) void scan_kernel(const int* cnt, int* offs, int n) {
    __shared__ int wsum[16];
    __shared__ int carry;
    int lane = threadIdx.x & 63;
    int w = threadIdx.x >> 6;
    if (threadIdx.x == 0) { carry = 0; offs[0] = 0; }
    __syncthreads();
    for (int base = 0; base < n; base += 1024) {
        int i = base + (int)threadIdx.x;
        int v = (i < n) ? cnt[i] : 0;
        int s = v;
        for (int d = 1; d < 64; d <<= 1) {
            int t = __shfl_up(s, d);
            if (lane >= d) s += t;
        }
        if (lane == 63) wsum[w] = s;
        __syncthreads();
        if (w == 0 && lane < 16) {
            int ws = wsum[lane];
            for (int d = 1; d < 16; d <<= 1) {
                int t = __shfl_up(ws, d);
                if (lane >= d) ws += t;
            }
            wsum[lane] = ws;
        }
        __syncthreads();
        int wofs = (w > 0) ? wsum[w - 1] : 0;
        int total = wsum[15];
        if (i < n) offs[i + 1] = carry + wofs + s;
        __syncthreads();
        if (threadIdx.x == 0) carry += total;
        __syncthreads();
    }
}

// ---------------- fill CSC with (row, norm, raw ea) -----------------------------
__global__ __launch_bounds__(256) void fill_kernel(const int* __restrict__ row,
                                                   const int* __restrict__ col,
                                                   const float* __restrict__ ew,
                                                   const float* __restrict__ dinv,
                                                   const int* __restrict__ offs, int* cursor,
                                                   int* cscr, float* cscw, float* cscea,
                                                   int E) {
    int e = blockIdx.x * 256 + threadIdx.x;
    if (e >= E) return;
    int r = row[e], c = col[e];
    int slot = offs[c] + atomicAdd(&cursor[c], 1);
    float w = ew[e];
    cscr[slot] = r;
    cscw[slot] = dinv[r] * w * dinv[c];
    cscea[slot] = w;
}

// ---------------- GCN aggregation from bf16 src, fp32 out, wave per node --------
// dst[i] = dinv[i]^2 * src[i] + sum_k w_k * src[r_k]
// F=128: lane holds 2 features (uint gather).  F=256: lane holds 4 (uint2 gather).
__global__ __launch_bounds__(256) void agg128_kernel(const uint32* __restrict__ src,
                                                     const float* __restrict__ dinv,
                                                     const int* __restrict__ offs,
                                                     const int* __restrict__ cscr,
                                                     const float* __restrict__ cscw,
                                                     float* __restrict__ dst) {
    int wave = threadIdx.x >> 6, lane = threadIdx.x & 63;
    int i = blockIdx.x * 4 + wave;
    if (i >= Nn) return;
    float di = dinv[i];
    float2 self = bfpair(src[(size_t)i * 64 + lane]);
    float ax = di * di * self.x, ay = di * di * self.y;
    int e0 = offs[i], e1 = offs[i + 1];
    int k = e0;
    for (; k + 4 <= e1; k += 4) {
        int r0 = cscr[k], r1 = cscr[k + 1], r2 = cscr[k + 2], r3 = cscr[k + 3];
        float w0 = cscw[k], w1 = cscw[k + 1], w2 = cscw[k + 2], w3 = cscw[k + 3];
        uint32 u0 = src[(size_t)r0 * 64 + lane];
        uint32 u1 = src[(size_t)r1 * 64 + lane];
        uint32 u2 = src[(size_t)r2 * 64 + lane];
        uint32 u3 = src[(size_t)r3 * 64 + lane];
        float2 t0 = bfpair(u0), t1 = bfpair(u1), t2 = bfpair(u2), t3 = bfpair(u3);
        ax = fmaf(w0, t0.x, ax); ay = fmaf(w0, t0.y, ay);
        ax = fmaf(w1, t1.x, ax); ay = fmaf(w1, t1.y, ay);
        ax = fmaf(w2, t2.x, ax); ay = fmaf(w2, t2.y, ay);
        ax = fmaf(w3, t3.x, ax); ay = fmaf(w3, t3.y, ay);
    }
    for (; k < e1; k++) {
        int r0 = cscr[k];
        float w0 = cscw[k];
        float2 t0 = bfpair(src[(size_t)r0 * 64 + lane]);
        ax = fmaf(w0, t0.x, ax); ay = fmaf(w0, t0.y, ay);
    }
    *(float2*)(dst + (size_t)i * 128 + lane * 2) = make_float2(ax, ay);
}

__global__ __launch_bounds__(256) void agg256_kernel(const uint2* __restrict__ src,
                                                     const float* __restrict__ dinv,
                                                     const int* __restrict__ offs,
                                                     const int* __restrict__ cscr,
                                                     const float* __restrict__ cscw,
                                                     float* __restrict__ dst) {
    int wave = threadIdx.x >> 6, lane = threadIdx.x & 63;
    int i = blockIdx.x * 4 + wave;
    if (i >= Nn) return;
    float di = dinv[i];
    uint2 su = src[(size_t)i * 64 + lane];
    float2 s0 = bfpair(su.x), s1 = bfpair(su.y);
    float a0 = di * di * s0.x, a1 = di * di * s0.y;
    float a2 = di * di * s1.x, a3 = di * di * s1.y;
    int e0 = offs[i], e1 = offs[i + 1];
    int k = e0;
    for (; k + 4 <= e1; k += 4) {
        int r0 = cscr[k], r1 = cscr[k + 1], r2 = cscr[k + 2], r3 = cscr[k + 3];
        float w0 = cscw[k], w1 = cscw[k + 1], w2 = cscw[k + 2], w3 = cscw[k + 3];
        uint2 u0 = src[(size_t)r0 * 64 + lane];
        uint2 u1 = src[(size_t)r1 * 64 + lane];
        uint2 u2 = src[(size_t)r2 * 64 + lane];
        uint2 u3 = src[(size_t)r3 * 64 + lane];
        float2 p, q;
        p = bfpair(u0.x); q = bfpair(u0.y);
        a0 = fmaf(w0, p.x, a0); a1 = fmaf(w0, p.y, a1);
        a2 = fmaf(w0, q.x, a2); a3 = fmaf(w0, q.y, a3);
        p = bfpair(u1.x); q = bfpair(u1.y);
        a0 = fmaf(w1, p.x, a0); a1 = fmaf(w1, p.y, a1);
        a2 = fmaf(w1, q.x, a2); a3 = fmaf(w1, q.y, a3);
        p = bfpair(u2.x); q = bfpair(u2.y);
        a0 = fmaf(w2, p.x, a0); a1 = fmaf(w2, p.y, a1);
        a2 = fmaf(w2, q.x, a2); a3 = fmaf(w2, q.y, a3);
        p = bfpair(u3.x); q = bfpair(u3.y);
        a0 = fmaf(w3, p.x, a0); a1 = fmaf(w3, p.y, a1);
        a2 = fmaf(w3, q.x, a2); a3 = fmaf(w3, q.y, a3);
    }
    for (; k < e1; k++) {
        int r0 = cscr[k];
        float w0 = cscw[k];
        uint2 u0 = src[(size_t)r0 * 64 + lane];
        float2 p = bfpair(u0.x), q = bfpair(u0.y);
        a0 = fmaf(w0, p.x, a0); a1 = fmaf(w0, p.y, a1);
        a2 = fmaf(w0, q.x, a2); a3 = fmaf(w0, q.y, a3);
    }
    *(float4*)(dst + (size_t)i * 256 + lane * 4) = make_float4(a0, a1, a2, a3);
}

// ---------------- fp32 tiled GEMM + fused bias/ReLU epilogue --------------------
#define BM 64
#define BN 64
#define BK 16
template <bool BF16OUT>
__global__ __launch_bounds__(256) void gemm_bias_relu_kernel(const float* __restrict__ A,
                                                             const float* __restrict__ W,
                                                             const float* __restrict__ bias,
                                                             float* __restrict__ Cf,
                                                             uint32* __restrict__ Cb,
                                                             int M, int K, int NC) {
    __shared__ float As[BK][BM];
    __shared__ float Bs[BK][BN];
    int t = threadIdx.x;
    int m0 = blockIdx.x * BM;
    int n0 = blockIdx.y * BN;
    int ty = t >> 4;
    int tx = t & 15;
    int lar = t >> 2;
    int lak = (t & 3) * 4;
    int lbk = t >> 4;
    int lbn = (t & 15) * 4;
    float acc[4][4] = {{0.f}};
    for (int k0 = 0; k0 < K; k0 += BK) {
        float4 av = make_float4(0.f, 0.f, 0.f, 0.f);
        int arow = m0 + lar;
        if (arow < M) av = *(const float4*)(A + (size_t)arow * K + k0 + lak);
        As[lak + 0][lar] = av.x;
        As[lak + 1][lar] = av.y;
        As[lak + 2][lar] = av.z;
        As[lak + 3][lar] = av.w;
        *(float4*)&Bs[lbk][lbn] = *(const float4*)(W + (size_t)(k0 + lbk) * NC + n0 + lbn);
        __syncthreads();
#pragma unroll
        for (int kk = 0; kk < BK; kk++) {
            float4 a4 = *(const float4*)&As[kk][ty << 2];
            float4 b4 = *(const float4*)&Bs[kk][tx << 2];
            float ar[4] = {a4.x, a4.y, a4.z, a4.w};
            float br[4] = {b4.x, b4.y, b4.z, b4.w};
#pragma unroll
            for (int r = 0; r < 4; r++)
#pragma unroll
                for (int c = 0; c < 4; c++)
                    acc[r][c] = fmaf(ar[r], br[c], acc[r][c]);
        }
        __syncthreads();
    }
    float4 b4 = *(const float4*)(bias + n0 + (tx << 2));
    float bb[4] = {b4.x, b4.y, b4.z, b4.w};
#pragma unroll
    for (int r = 0; r < 4; r++) {
        int rowi = m0 + (ty << 2) + r;
        if (rowi < M) {
            float o0 = fmaxf(acc[r][0] + bb[0], 0.0f);
            float o1 = fmaxf(acc[r][1] + bb[1], 0.0f);
            float o2 = fmaxf(acc[r][2] + bb[2], 0.0f);
            float o3 = fmaxf(acc[r][3] + bb[3], 0.0f);
            if (BF16OUT) {
                uint2 pk;
                pk.x = packbf(o0, o1);
                pk.y = packbf(o2, o3);
                *(uint2*)(Cb + ((size_t)rowi * NC + n0 + (tx << 2)) / 2) = pk;
            } else {
                *(float4*)(Cf + (size_t)rowi * NC + n0 + (tx << 2)) =
                    make_float4(o0, o1, o2, o3);
            }
        }
    }
}

// ---------------- fused GEMM3 + softmax + cluster/ca partials -------------------
__global__ __launch_bounds__(256) void softmax_kernel(const float* __restrict__ h2,
                                                      const float* __restrict__ Wm,
                                                      const float* __restrict__ bm,
                                                      const float* __restrict__ degrow,
                                                      float* __restrict__ s_out,
                                                      ushort16* __restrict__ s_bf,
                                                      float* __restrict__ g_clsz,
                                                      float* __restrict__ g_ca) {
    __shared__ float sh[16 * Hid];
    __shared__ float redc[4][Cc];
    __shared__ float reda[4][Cc];
    int t = threadIdx.x;
    int rb = blockIdx.x * 16;
    const float4* src = (const float4*)(h2 + (size_t)rb * Hid);
    float4* dst = (float4*)sh;
    for (int j = t; j < 16 * Hid / 4; j += 256) dst[j] = src[j];
    __syncthreads();
    int wave = t >> 6, f = t & 63;
    float a0 = bm[f], a1 = a0, a2 = a0, a3 = a0;
    const float* hrow = &sh[(wave * 4) * Hid];
#pragma unroll 4
    for (int k = 0; k < Hid; k++) {
        float w = Wm[k * Cc + f];
        a0 = fmaf(hrow[k], w, a0);
        a1 = fmaf(hrow[Hid + k], w, a1);
        a2 = fmaf(hrow[2 * Hid + k], w, a2);
        a3 = fmaf(hrow[3 * Hid + k], w, a3);
    }
    float av[4] = {a0, a1, a2, a3};
    float pc = 0.0f, pa = 0.0f;
#pragma unroll
    for (int r = 0; r < 4; r++) {
        int rowi = rb + wave * 4 + r;
        float v = av[r];
        float mx = v;
        for (int o = 32; o; o >>= 1) mx = fmaxf(mx, __shfl_xor(mx, o));
        float e = __expf(v - mx);
        float ssum = e;
        for (int o = 32; o; o >>= 1) ssum += __shfl_xor(ssum, o);
        float sv = e / ssum;
        s_out[(size_t)rowi * Cc + f] = sv;
        s_bf[(size_t)rowi * Cc + f] = f2bf(sv);
        pc += sv;
        pa += sv * degrow[rowi];
    }
    redc[wave][f] = pc;
    reda[wave][f] = pa;
    __syncthreads();
    if (wave == 0) {
        float c = redc[0][f] + redc[1][f] + redc[2][f] + redc[3][f];
        float a = reda[0][f] + reda[1][f] + reda[2][f] + reda[3][f];
        atomicAdd(&g_clsz[f], c);
        atomicAdd(&g_ca[f], a);
    }
}

// ---------------- trace via CSC: wave per node, bf16 s --------------------------
// trace = sum_c dot(s[c], sum_{e into c} ea_e * s[row_e])
__global__ __launch_bounds__(256) void trace_csc_kernel(const int* __restrict__ offs,
                                                        const int* __restrict__ cscr,
                                                        const float* __restrict__ cscea,
                                                        const uint32* __restrict__ sbf,
                                                        float* g_trace) {
    int wave = threadIdx.x >> 6, lane = threadIdx.x & 63;
    int c = blockIdx.x * 4 + wave;
    float a = 0.0f;
    if (c < Nn) {
        int l5 = lane & 31;
        int q = lane >> 5;                        // half-wave: 0 or 1
        float2 sc = bfpair(sbf[(size_t)c * 32 + l5]);
        int e0 = offs[c], e1 = offs[c + 1];
        int k = e0;
        for (; k + 8 <= e1; k += 8) {
            int kk = k + q;
            int r0 = cscr[kk], r1 = cscr[kk + 2], r2 = cscr[kk + 4], r3 = cscr[kk + 6];
            float w0 = cscea[kk], w1 = cscea[kk + 2], w2 = cscea[kk + 4], w3 = cscea[kk + 6];
            uint32 u0 = sbf[(size_t)r0 * 32 + l5];
            uint32 u1 = sbf[(size_t)r1 * 32 + l5];
            uint32 u2 = sbf[(size_t)r2 * 32 + l5];
            uint32 u3 = sbf[(size_t)r3 * 32 + l5];
            float2 p;
            p = bfpair(u0); a = fmaf(w0, p.x * sc.x + p.y * sc.y, a);
            p = bfpair(u1); a = fmaf(w1, p.x * sc.x + p.y * sc.y, a);
            p = bfpair(u2); a = fmaf(w2, p.x * sc.x + p.y * sc.y, a);
            p = bfpair(u3); a = fmaf(w3, p.x * sc.x + p.y * sc.y, a);
        }
        for (; k + 2 <= e1; k += 2) {
            int kk = k + q;
            int r0 = cscr[kk];
            float w0 = cscea[kk];
            float2 p = bfpair(sbf[(size_t)r0 * 32 + l5]);
            a = fmaf(w0, p.x * sc.x + p.y * sc.y, a);
        }
        if (k < e1 && q == 0) {                   // odd leftover: half-wave 0 only
            int r0 = cscr[k];
            float w0 = cscea[k];
            float2 p = bfpair(sbf[(size_t)r0 * 32 + l5]);
            a = fmaf(w0, p.x * sc.x + p.y * sc.y, a);
        }
    }
    for (int o = 32; o; o >>= 1) a += __shfl_xor(a, o);
    __shared__ float sred[4];
    if (lane == 0) sred[wave] = a;
    __syncthreads();
    if (threadIdx.x == 0)
        atomicAdd(g_trace, sred[0] + sred[1] + sred[2] + sred[3]);
}

// ---------------- final scalars -------------------------------------------------
__global__ void final_kernel(const float* acc, float* out_tail) {
    float m = acc[128] * 0.5f;
    float caca = 0.0f, cc = 0.0f;
    for (int k = 0; k < Cc; k++) {
        caca += acc[64 + k] * acc[64 + k];
        cc += acc[k] * acc[k];
    }
    float tn = caca / (2.0f * m);
    float spec = -(acc[129] - tn) / (2.0f * m);
    float clust = sqrtf(cc) / (float)Nn * 8.0f - 1.0f;   // sqrt(C)=8
    out_tail[0] = 100.0f * (spec + clust);
    out_tail[1] = 100.0f * spec;
    out_tail[2] = 100.0f * clust;
}

extern "C" void kernel_launch(void* const* d_in, const int* in_sizes, int n_in,
                              void* d_out, int out_size, void* d_ws, size_t ws_size,
                              hipStream_t stream) {
    const float* x  = (const float*)d_in[0];
    const float* ea = (const float*)d_in[1];
    const float* W1 = (const float*)d_in[2];
    const float* b1 = (const float*)d_in[3];
    const float* W2 = (const float*)d_in[4];
    const float* b2 = (const float*)d_in[5];
    const float* Wm = (const float*)d_in[6];
    const float* bm = (const float*)d_in[7];
    const void*  ei = d_in[8];
    float* out = (float*)d_out;

    size_t off = 0;
    auto carve = [&](size_t bytes) -> void* {
        void* p = (char*)d_ws + off;
        off += (bytes + 255) & ~(size_t)255;
        return p;
    };
    float*  acc    = (float*)carve(132 * 4);
    int*    flag   = (int*)carve(4);
    float*  deg    = (float*)carve(Nn * 4);
    float*  dinv   = (float*)carve(Nn * 4);
    float*  degrow = (float*)carve(Nn * 4);
    int*    cnt    = (int*)carve(Nn * 4);
    int*    offs   = (int*)carve((Nn + 1) * 4);
    int*    cursor = (int*)carve(Nn * 4);
    int*    ebuf   = (int*)carve((size_t)2 * Ee * 4);
    int*    cscr   = (int*)carve(Ee * 4);
    float*  cscw   = (float*)carve(Ee * 4);
    float*  cscea  = (float*)carve(Ee * 4);
    uint32* xb     = (uint32*)carve((size_t)Nn * Fin / 2 * 4);   // x bf16 packed
    uint32* h1b    = (uint32*)carve((size_t)Nn * Hid / 2 * 4);   // h1 bf16 packed
    uint32* sb     = (uint32*)carve((size_t)Nn * Cc / 2 * 4);    // s bf16 packed
    float*  bufA   = (float*)carve((size_t)Nn * Fin * 4);        // agg1 out (fp32)
    float*  bufB   = (float*)carve((size_t)Nn * Hid * 4);        // agg2 out (fp32)
    float*  bufC   = (float*)carve((size_t)Nn * Hid * 4);        // h2 (fp32)
    int* row32 = ebuf;
    int* col32 = ebuf + Ee;

    init_kernel<<<(Nn + 255) / 256, 256, 0, stream>>>(deg, degrow, cnt, cursor, acc);
    detect_kernel<<<1, 256, 0, stream>>>((const int*)ei, flag);
    convert_kernel<<<(2 * Ee + 255) / 256, 256, 0, stream>>>(ei, flag, ebuf, 2 * Ee);
    edge_stats_kernel<<<(Ee + 255) / 256, 256, 0, stream>>>(row32, col32, ea, deg, degrow,
                                                            cnt, acc + 128, Ee);
    dinv_kernel<<<(Nn + 255) / 256, 256, 0, stream>>>(deg, dinv);
    scan_kernel<<<1, 1024, 0, stream>>>(cnt, offs, Nn);
    fill_kernel<<<(Ee + 255) / 256, 256, 0, stream>>>(row32, col32, ea, dinv, offs, cursor,
                                                      cscr, cscw, cscea, Ee);
    xbf_kernel<<<(Nn * Fin / 2 + 255) / 256, 256, 0, stream>>>(x, xb, Nn * Fin / 2);

    // layer 1: xa = agg(x_bf16) [F=128], h1 = relu(xa @ W1 + b1) -> bf16
    agg128_kernel<<<(Nn + 3) / 4, 256, 0, stream>>>(xb, dinv, offs, cscr, cscw, bufA);
    dim3 ggrid((Nn + BM - 1) / BM, Hid / BN);
    gemm_bias_relu_kernel<true><<<ggrid, 256, 0, stream>>>(bufA, W1, b1, nullptr, h1b,
                                                           Nn, Fin, Hid);
    // layer 2: h1a = agg(h1_bf16) [F=256], h2 = relu(h1a @ W2 + b2) -> fp32
    agg256_kernel<<<(Nn + 3) / 4, 256, 0, stream>>>((const uint2*)h1b, dinv, offs, cscr,
                                                    cscw, bufB);
    gemm_bias_relu_kernel<false><<<ggrid, 256, 0, stream>>>(bufB, W2, b2, bufC, nullptr,
                                                            Nn, Hid, Hid);

    softmax_kernel<<<Nn / 16, 256, 0, stream>>>(bufC, Wm, bm, degrow, out, (ushort16*)sb,
                                                acc, acc + 64);
    trace_csc_kernel<<<(Nn + 3) / 4, 256, 0, stream>>>(offs, cscr, cscea, sb, acc + 129);
    final_kernel<<<1, 1, 0, stream>>>(acc, out + (size_t)Nn * Cc);
}

// Round 4
// 266.309 us; speedup vs baseline: 1.4213x; 1.0403x over previous
//
#include <hip/hip_runtime.h>
#include <hip/hip_bf16.h>

#define Nn 10000
#define Ee 160000
#define Fin 128
#define Hid 256
#define Cc 64

typedef unsigned int uint32;
typedef unsigned short ushort16;
typedef __attribute__((ext_vector_type(8))) short short8;
typedef __attribute__((ext_vector_type(4))) float float4v;

__device__ inline float2 bfpair(uint32 u) {
    float2 r;
    r.x = __uint_as_float(u << 16);
    r.y = __uint_as_float(u & 0xffff0000u);
    return r;
}
__device__ inline ushort16 f2bf(float f) {
    __hip_bfloat16 h = __float2bfloat16(f);
    union { __hip_bfloat16 h; ushort16 u; } cv;
    cv.h = h;
    return cv.u;
}
__device__ inline uint32 packbf(float a, float b) {
    return (uint32)f2bf(a) | ((uint32)f2bf(b) << 16);
}

// ---------------- init: zero accumulators, deg=1 (self loop), counts=0 ----------
__global__ __launch_bounds__(256) void init_kernel(float* deg, float* degrow, int* cnt,
                                                   int* cursor, float* acc) {
    int i = blockIdx.x * 256 + threadIdx.x;
    if (i < Nn) { deg[i] = 1.0f; degrow[i] = 0.0f; cnt[i] = 0; cursor[i] = 0; }
    if (blockIdx.x == 0 && threadIdx.x < 132) acc[threadIdx.x] = 0.0f;
}

// ---------------- detect int64 vs int32 storage of edge_index -------------------
__global__ void detect_kernel(const int* w, int* flag) {
    __shared__ int any;
    if (threadIdx.x == 0) any = 0;
    __syncthreads();
    for (int j = threadIdx.x; j < 1024; j += 256) {
        if (w[2 * j + 1] != 0) atomicOr(&any, 1);
    }
    __syncthreads();
    if (threadIdx.x == 0) *flag = (any == 0) ? 1 : 0;   // 1 => int64 layout
}

__global__ __launch_bounds__(256) void convert_kernel(const void* ei, const int* flag,
                                                      int* out, int n2e) {
    int i = blockIdx.x * 256 + threadIdx.x;
    if (i >= n2e) return;
    if (*flag) out[i] = (int)((const long long*)ei)[i];
    else       out[i] = ((const int*)ei)[i];
}

// ---------------- x -> bf16 packed ----------------------------------------------
__global__ __launch_bounds__(256) void xbf_kernel(const float* __restrict__ x,
                                                  uint32* __restrict__ xb, int npairs) {
    int i = blockIdx.x * 256 + threadIdx.x;
    if (i >= npairs) return;
    float2 v = *(const float2*)(x + 2 * (size_t)i);
    xb[i] = packbf(v.x, v.y);
}

// ---------------- Wm -> MFMA B-fragment layout (bf16), 8 ktiles x 4 ntiles ------
// frag[((t*4+n)*64+l)*8+j] = bf16(Wm[(t*32+(l>>4)*8+j)*Cc + n*16+(l&15)])
__global__ __launch_bounds__(256) void wmfrag_kernel(const float* __restrict__ Wm,
                                                     ushort16* __restrict__ frag) {
    int idx = blockIdx.x * 256 + threadIdx.x;   // 0..2047
    if (idx >= 8 * 4 * 64) return;
    int l = idx & 63;
    int n = (idx >> 6) & 3;
    int t = idx >> 8;
    int k0 = t * 32 + (l >> 4) * 8;
    int c = n * 16 + (l & 15);
#pragma unroll
    for (int j = 0; j < 8; j++) frag[idx * 8 + j] = f2bf(Wm[(size_t)(k0 + j) * Cc + c]);
}

// ---------------- edge stats: weighted in-degree, adj row sums, CSC counts ------
__global__ __launch_bounds__(256) void edge_stats_kernel(const int* __restrict__ row,
                                                         const int* __restrict__ col,
                                                         const float* __restrict__ ew,
                                                         float* deg, float* degrow, int* cnt,
                                                         float* g_sum_ea, int E) {
    int e = blockIdx.x * 256 + threadIdx.x;
    float v = 0.0f;
    if (e < E) {
        int r = row[e], c = col[e];
        float w = ew[e];
        v = w;
        atomicAdd(&deg[c], w);
        atomicAdd(&degrow[r], w);
        atomicAdd(&cnt[c], 1);
    }
    for (int off = 32; off; off >>= 1) v += __shfl_xor(v, off);
    __shared__ float sred[4];
    if ((threadIdx.x & 63) == 0) sred[threadIdx.x >> 6] = v;
    __syncthreads();
    if (threadIdx.x == 0) atomicAdd(g_sum_ea, sred[0] + sred[1] + sred[2] + sred[3]);
}

__global__ __launch_bounds__(256) void dinv_kernel(const float* deg, float* dinv) {
    int i = blockIdx.x * 256 + threadIdx.x;
    if (i < Nn) dinv[i] = rsqrtf(deg[i]);
}

// ---------------- single-block exclusive scan via wave shuffles -----------------
__global__ __launch_bounds__(1024) void scan_kernel(const int* cnt, int* offs, int n) {
    __shared__ int wsum[16];
    __shared__ int carry;
    int lane = threadIdx.x & 63;
    int w = threadIdx.x >> 6;
    if (threadIdx.x == 0) { carry = 0; offs[0] = 0; }
    __syncthreads();
    for (int base = 0; base < n; base += 1024) {
        int i = base + (int)threadIdx.x;
        int v = (i < n) ? cnt[i] : 0;
        int s = v;
        for (int d = 1; d < 64; d <<= 1) {
            int t = __shfl_up(s, d);
            if (lane >= d) s += t;
        }
        if (lane == 63) wsum[w] = s;
        __syncthreads();
        if (w == 0 && lane < 16) {
            int ws = wsum[lane];
            for (int d = 1; d < 16; d <<= 1) {
                int t = __shfl_up(ws, d);
                if (lane >= d) ws += t;
            }
            wsum[lane] = ws;
        }
        __syncthreads();
        int wofs = (w > 0) ? wsum[w - 1] : 0;
        int total = wsum[15];
        if (i < n) offs[i + 1] = carry + wofs + s;
        __syncthreads();
        if (threadIdx.x == 0) carry += total;
        __syncthreads();
    }
}

// ---------------- fill CSC with (row, norm, raw ea) -----------------------------
__global__ __launch_bounds__(256) void fill_kernel(const int* __restrict__ row,
                                                   const int* __restrict__ col,
                                                   const float* __restrict__ ew,
                                                   const float* __restrict__ dinv,
                                                   const int* __restrict__ offs, int* cursor,
                                                   int* cscr, float* cscw, float* cscea,
                                                   int E) {
    int e = blockIdx.x * 256 + threadIdx.x;
    if (e >= E) return;
    int r = row[e], c = col[e];
    int slot = offs[c] + atomicAdd(&cursor[c], 1);
    float w = ew[e];
    cscr[slot] = r;
    cscw[slot] = dinv[r] * w * dinv[c];
    cscea[slot] = w;
}

// ---------------- GCN aggregation from bf16 src, fp32 out, wave per node --------
__global__ __launch_bounds__(256) void agg128_kernel(const uint32* __restrict__ src,
                                                     const float* __restrict__ dinv,
                                                     const int* __restrict__ offs,
                                                     const int* __restrict__ cscr,
                                                     const float* __restrict__ cscw,
                                                     float* __restrict__ dst) {
    int wave = threadIdx.x >> 6, lane = threadIdx.x & 63;
    int i = blockIdx.x * 4 + wave;
    if (i >= Nn) return;
    float di = dinv[i];
    float2 self = bfpair(src[(size_t)i * 64 + lane]);
    float ax = di * di * self.x, ay = di * di * self.y;
    int e0 = offs[i], e1 = offs[i + 1];
    int k = e0;
    for (; k + 4 <= e1; k += 4) {
        int r0 = cscr[k], r1 = cscr[k + 1], r2 = cscr[k + 2], r3 = cscr[k + 3];
        float w0 = cscw[k], w1 = cscw[k + 1], w2 = cscw[k + 2], w3 = cscw[k + 3];
        uint32 u0 = src[(size_t)r0 * 64 + lane];
        uint32 u1 = src[(size_t)r1 * 64 + lane];
        uint32 u2 = src[(size_t)r2 * 64 + lane];
        uint32 u3 = src[(size_t)r3 * 64 + lane];
        float2 t0 = bfpair(u0), t1 = bfpair(u1), t2 = bfpair(u2), t3 = bfpair(u3);
        ax = fmaf(w0, t0.x, ax); ay = fmaf(w0, t0.y, ay);
        ax = fmaf(w1, t1.x, ax); ay = fmaf(w1, t1.y, ay);
        ax = fmaf(w2, t2.x, ax); ay = fmaf(w2, t2.y, ay);
        ax = fmaf(w3, t3.x, ax); ay = fmaf(w3, t3.y, ay);
    }
    for (; k < e1; k++) {
        int r0 = cscr[k];
        float w0 = cscw[k];
        float2 t0 = bfpair(src[(size_t)r0 * 64 + lane]);
        ax = fmaf(w0, t0.x, ax); ay = fmaf(w0, t0.y, ay);
    }
    *(float2*)(dst + (size_t)i * 128 + lane * 2) = make_float2(ax, ay);
}

__global__ __launch_bounds__(256) void agg256_kernel(const uint2* __restrict__ src,
                                                     const float* __restrict__ dinv,
                                                     const int* __restrict__ offs,
                                                     const int* __restrict__ cscr,
                                                     const float* __restrict__ cscw,
                                                     float* __restrict__ dst) {
    int wave = threadIdx.x >> 6, lane = threadIdx.x & 63;
    int i = blockIdx.x * 4 + wave;
    if (i >= Nn) return;
    float di = dinv[i];
    uint2 su = src[(size_t)i * 64 + lane];
    float2 s0 = bfpair(su.x), s1 = bfpair(su.y);
    float a0 = di * di * s0.x, a1 = di * di * s0.y;
    float a2 = di * di * s1.x, a3 = di * di * s1.y;
    int e0 = offs[i], e1 = offs[i + 1];
    int k = e0;
    for (; k + 4 <= e1; k += 4) {
        int r0 = cscr[k], r1 = cscr[k + 1], r2 = cscr[k + 2], r3 = cscr[k + 3];
        float w0 = cscw[k], w1 = cscw[k + 1], w2 = cscw[k + 2], w3 = cscw[k + 3];
        uint2 u0 = src[(size_t)r0 * 64 + lane];
        uint2 u1 = src[(size_t)r1 * 64 + lane];
        uint2 u2 = src[(size_t)r2 * 64 + lane];
        uint2 u3 = src[(size_t)r3 * 64 + lane];
        float2 p, q;
        p = bfpair(u0.x); q = bfpair(u0.y);
        a0 = fmaf(w0, p.x, a0); a1 = fmaf(w0, p.y, a1);
        a2 = fmaf(w0, q.x, a2); a3 = fmaf(w0, q.y, a3);
        p = bfpair(u1.x); q = bfpair(u1.y);
        a0 = fmaf(w1, p.x, a0); a1 = fmaf(w1, p.y, a1);
        a2 = fmaf(w1, q.x, a2); a3 = fmaf(w1, q.y, a3);
        p = bfpair(u2.x); q = bfpair(u2.y);
        a0 = fmaf(w2, p.x, a0); a1 = fmaf(w2, p.y, a1);
        a2 = fmaf(w2, q.x, a2); a3 = fmaf(w2, q.y, a3);
        p = bfpair(u3.x); q = bfpair(u3.y);
        a0 = fmaf(w3, p.x, a0); a1 = fmaf(w3, p.y, a1);
        a2 = fmaf(w3, q.x, a2); a3 = fmaf(w3, q.y, a3);
    }
    for (; k < e1; k++) {
        int r0 = cscr[k];
        float w0 = cscw[k];
        uint2 u0 = src[(size_t)r0 * 64 + lane];
        float2 p = bfpair(u0.x), q = bfpair(u0.y);
        a0 = fmaf(w0, p.x, a0); a1 = fmaf(w0, p.y, a1);
        a2 = fmaf(w0, q.x, a2); a3 = fmaf(w0, q.y, a3);
    }
    *(float4*)(dst + (size_t)i * 256 + lane * 4) = make_float4(a0, a1, a2, a3);
}

// ---------------- fp32 tiled GEMM + fused bias/ReLU epilogue --------------------
#define BM 64
#define BN 64
#define BK 16
template <bool BF16OUT>
__global__ __launch_bounds__(256) void gemm_bias_relu_kernel(const float* __restrict__ A,
                                                             const float* __restrict__ W,
                                                             const float* __restrict__ bias,
                                                             float* __restrict__ Cf,
                                                             uint32* __restrict__ Cb,
                                                             int M, int K, int NC) {
    __shared__ float As[BK][BM];
    __shared__ float Bs[BK][BN];
    int t = threadIdx.x;
    int m0 = blockIdx.x * BM;
    int n0 = blockIdx.y * BN;
    int ty = t >> 4;
    int tx = t & 15;
    int lar = t >> 2;
    int lak = (t & 3) * 4;
    int lbk = t >> 4;
    int lbn = (t & 15) * 4;
    float acc[4][4] = {{0.f}};
    for (int k0 = 0; k0 < K; k0 += BK) {
        float4 av = make_float4(0.f, 0.f, 0.f, 0.f);
        int arow = m0 + lar;
        if (arow < M) av = *(const float4*)(A + (size_t)arow * K + k0 + lak);
        As[lak + 0][lar] = av.x;
        As[lak + 1][lar] = av.y;
        As[lak + 2][lar] = av.z;
        As[lak + 3][lar] = av.w;
        *(float4*)&Bs[lbk][lbn] = *(const float4*)(W + (size_t)(k0 + lbk) * NC + n0 + lbn);
        __syncthreads();
#pragma unroll
        for (int kk = 0; kk < BK; kk++) {
            float4 a4 = *(const float4*)&As[kk][ty << 2];
            float4 b4 = *(const float4*)&Bs[kk][tx << 2];
            float ar[4] = {a4.x, a4.y, a4.z, a4.w};
            float br[4] = {b4.x, b4.y, b4.z, b4.w};
#pragma unroll
            for (int r = 0; r < 4; r++)
#pragma unroll
                for (int c = 0; c < 4; c++)
                    acc[r][c] = fmaf(ar[r], br[c], acc[r][c]);
        }
        __syncthreads();
    }
    float4 b4 = *(const float4*)(bias + n0 + (tx << 2));
    float bb[4] = {b4.x, b4.y, b4.z, b4.w};
#pragma unroll
    for (int r = 0; r < 4; r++) {
        int rowi = m0 + (ty << 2) + r;
        if (rowi < M) {
            float o0 = fmaxf(acc[r][0] + bb[0], 0.0f);
            float o1 = fmaxf(acc[r][1] + bb[1], 0.0f);
            float o2 = fmaxf(acc[r][2] + bb[2], 0.0f);
            float o3 = fmaxf(acc[r][3] + bb[3], 0.0f);
            if (BF16OUT) {
                uint2 pk;
                pk.x = packbf(o0, o1);
                pk.y = packbf(o2, o3);
                *(uint2*)(Cb + ((size_t)rowi * NC + n0 + (tx << 2)) / 2) = pk;
            } else {
                *(float4*)(Cf + (size_t)rowi * NC + n0 + (tx << 2)) =
                    make_float4(o0, o1, o2, o3);
            }
        }
    }
}

// ---------------- MFMA softmax: logits = h2b @ Wm + bm, softmax, partials -------
// wave handles 16 rows x 64 cols: 4 acc tiles (N), K-loop 8 x mfma_16x16x32_bf16.
// A frag: lane -> row=lane&15, k=quad*8+j. C/D: col=lane&15, row=quad*4+reg.
__global__ __launch_bounds__(256) void softmax_mfma_kernel(const ushort16* __restrict__ h2b,
                                                           const short8* __restrict__ wfrag,
                                                           const float* __restrict__ bm,
                                                           const float* __restrict__ degrow,
                                                           float* __restrict__ s_out,
                                                           ushort16* __restrict__ s_bf,
                                                           float* __restrict__ g_clsz,
                                                           float* __restrict__ g_ca) {
    int wave = threadIdx.x >> 6, lane = threadIdx.x & 63;
    int rowbase = (blockIdx.x * 4 + wave) * 16;
    if (rowbase >= Nn) return;
    int quad = lane >> 4, l4 = lane & 15;
    float4v acc[4];
#pragma unroll
    for (int n = 0; n < 4; n++) acc[n] = (float4v){0.f, 0.f, 0.f, 0.f};
    const short8* arow = (const short8*)(h2b + (size_t)(rowbase + l4) * Hid + quad * 8);
#pragma unroll
    for (int t = 0; t < 8; t++) {
        short8 a = arow[t * 4];                 // k0 = t*32 (+quad*8 in base), /8 shorts
        const short8* bt = wfrag + (size_t)t * 4 * 64 + lane;
#pragma unroll
        for (int n = 0; n < 4; n++) {
            acc[n] = __builtin_amdgcn_mfma_f32_16x16x32_bf16(a, bt[n * 64], acc[n], 0, 0, 0);
        }
    }
    // bias
    float sv[4][4];
#pragma unroll
    for (int n = 0; n < 4; n++) {
        float bv = bm[n * 16 + l4];
#pragma unroll
        for (int r = 0; r < 4; r++) sv[n][r] = acc[n][r] + bv;
    }
    // row max over 64 cols: per-reg max over tiles, then over the 16-lane group
#pragma unroll
    for (int r = 0; r < 4; r++) {
        float m = fmaxf(fmaxf(sv[0][r], sv[1][r]), fmaxf(sv[2][r], sv[3][r]));
        for (int o = 8; o; o >>= 1) m = fmaxf(m, __shfl_xor(m, o));
        float ssum = 0.f;
#pragma unroll
        for (int n = 0; n < 4; n++) {
            sv[n][r] = __expf(sv[n][r] - m);
            ssum += sv[n][r];
        }
        for (int o = 8; o; o >>= 1) ssum += __shfl_xor(ssum, o);
        float inv = 1.0f / ssum;
#pragma unroll
        for (int n = 0; n < 4; n++) sv[n][r] *= inv;
    }
    // write s (fp32 for output, bf16 for trace)
#pragma unroll
    for (int r = 0; r < 4; r++) {
        int rowi = rowbase + quad * 4 + r;
#pragma unroll
        for (int n = 0; n < 4; n++) {
            s_out[(size_t)rowi * Cc + n * 16 + l4] = sv[n][r];
            s_bf[(size_t)rowi * Cc + n * 16 + l4] = f2bf(sv[n][r]);
        }
    }
    // column partials: cluster_size and ca = s^T degrees
    float dg[4];
#pragma unroll
    for (int r = 0; r < 4; r++) dg[r] = degrow[rowbase + quad * 4 + r];
#pragma unroll
    for (int n = 0; n < 4; n++) {
        float pc = sv[n][0] + sv[n][1] + sv[n][2] + sv[n][3];
        float pa = sv[n][0] * dg[0] + sv[n][1] * dg[1] + sv[n][2] * dg[2] + sv[n][3] * dg[3];
        pc += __shfl_xor(pc, 16); pc += __shfl_xor(pc, 32);
        pa += __shfl_xor(pa, 16); pa += __shfl_xor(pa, 32);
        if (quad == 0) {
            atomicAdd(&g_clsz[n * 16 + l4], pc);
            atomicAdd(&g_ca[n * 16 + l4], pa);
        }
    }
}

// ---------------- trace via CSC: wave per node, bf16 s --------------------------
__global__ __launch_bounds__(256) void trace_csc_kernel(const int* __restrict__ offs,
                                                        const int* __restrict__ cscr,
                                                        const float* __restrict__ cscea,
                                                        const uint32* __restrict__ sbf,
                                                        float* g_trace) {
    int wave = threadIdx.x >> 6, lane = threadIdx.x & 63;
    int c = blockIdx.x * 4 + wave;
    float a = 0.0f;
    if (c < Nn) {
        int l5 = lane & 31;
        int q = lane >> 5;
        float2 sc = bfpair(sbf[(size_t)c * 32 + l5]);
        int e0 = offs[c], e1 = offs[c + 1];
        int k = e0;
        for (; k + 8 <= e1; k += 8) {
            int kk = k + q;
            int r0 = cscr[kk], r1 = cscr[kk + 2], r2 = cscr[kk + 4], r3 = cscr[kk + 6];
            float w0 = cscea[kk], w1 = cscea[kk + 2], w2 = cscea[kk + 4], w3 = cscea[kk + 6];
            uint32 u0 = sbf[(size_t)r0 * 32 + l5];
            uint32 u1 = sbf[(size_t)r1 * 32 + l5];
            uint32 u2 = sbf[(size_t)r2 * 32 + l5];
            uint32 u3 = sbf[(size_t)r3 * 32 + l5];
            float2 p;
            p = bfpair(u0); a = fmaf(w0, p.x * sc.x + p.y * sc.y, a);
            p = bfpair(u1); a = fmaf(w1, p.x * sc.x + p.y * sc.y, a);
            p = bfpair(u2); a = fmaf(w2, p.x * sc.x + p.y * sc.y, a);
            p = bfpair(u3); a = fmaf(w3, p.x * sc.x + p.y * sc.y, a);
        }
        for (; k + 2 <= e1; k += 2) {
            int kk = k + q;
            int r0 = cscr[kk];
            float w0 = cscea[kk];
            float2 p = bfpair(sbf[(size_t)r0 * 32 + l5]);
            a = fmaf(w0, p.x * sc.x + p.y * sc.y, a);
        }
        if (k < e1 && q == 0) {
            int r0 = cscr[k];
            float w0 = cscea[k];
            float2 p = bfpair(sbf[(size_t)r0 * 32 + l5]);
            a = fmaf(w0, p.x * sc.x + p.y * sc.y, a);
        }
    }
    for (int o = 32; o; o >>= 1) a += __shfl_xor(a, o);
    __shared__ float sred[4];
    if (lane == 0) sred[wave] = a;
    __syncthreads();
    if (threadIdx.x == 0)
        atomicAdd(g_trace, sred[0] + sred[1] + sred[2] + sred[3]);
}

// ---------------- final scalars -------------------------------------------------
__global__ void final_kernel(const float* acc, float* out_tail) {
    float m = acc[128] * 0.5f;
    float caca = 0.0f, cc = 0.0f;
    for (int k = 0; k < Cc; k++) {
        caca += acc[64 + k] * acc[64 + k];
        cc += acc[k] * acc[k];
    }
    float tn = caca / (2.0f * m);
    float spec = -(acc[129] - tn) / (2.0f * m);
    float clust = sqrtf(cc) / (float)Nn * 8.0f - 1.0f;   // sqrt(C)=8
    out_tail[0] = 100.0f * (spec + clust);
    out_tail[1] = 100.0f * spec;
    out_tail[2] = 100.0f * clust;
}

extern "C" void kernel_launch(void* const* d_in, const int* in_sizes, int n_in,
                              void* d_out, int out_size, void* d_ws, size_t ws_size,
                              hipStream_t stream) {
    const float* x  = (const float*)d_in[0];
    const float* ea = (const float*)d_in[1];
    const float* W1 = (const float*)d_in[2];
    const float* b1 = (const float*)d_in[3];
    const float* W2 = (const float*)d_in[4];
    const float* b2 = (const float*)d_in[5];
    const float* Wm = (const float*)d_in[6];
    const float* bm = (const float*)d_in[7];
    const void*  ei = d_in[8];
    float* out = (float*)d_out;

    size_t off = 0;
    auto carve = [&](size_t bytes) -> void* {
        void* p = (char*)d_ws + off;
        off += (bytes + 255) & ~(size_t)255;
        return p;
    };
    float*  acc    = (float*)carve(132 * 4);
    int*    flag   = (int*)carve(4);
    float*  deg    = (float*)carve(Nn * 4);
    float*  dinv   = (float*)carve(Nn * 4);
    float*  degrow = (float*)carve(Nn * 4);
    int*    cnt    = (int*)carve(Nn * 4);
    int*    offs   = (int*)carve((Nn + 1) * 4);
    int*    cursor = (int*)carve(Nn * 4);
    int*    ebuf   = (int*)carve((size_t)2 * Ee * 4);
    int*    cscr   = (int*)carve(Ee * 4);
    float*  cscw   = (float*)carve(Ee * 4);
    float*  cscea  = (float*)carve(Ee * 4);
    uint32* xb     = (uint32*)carve((size_t)Nn * Fin / 2 * 4);   // x bf16 packed
    uint32* h1b    = (uint32*)carve((size_t)Nn * Hid / 2 * 4);   // h1 bf16 packed
    uint32* h2b    = (uint32*)carve((size_t)Nn * Hid / 2 * 4);   // h2 bf16 packed
    uint32* sb     = (uint32*)carve((size_t)Nn * Cc / 2 * 4);    // s bf16 packed
    ushort16* wfrag = (ushort16*)carve(8 * 4 * 64 * 8 * 2);      // Wm MFMA frags
    float*  bufA   = (float*)carve((size_t)Nn * Fin * 4);        // agg1 out (fp32)
    float*  bufB   = (float*)carve((size_t)Nn * Hid * 4);        // agg2 out (fp32)
    int* row32 = ebuf;
    int* col32 = ebuf + Ee;

    init_kernel<<<(Nn + 255) / 256, 256, 0, stream>>>(deg, degrow, cnt, cursor, acc);
    detect_kernel<<<1, 256, 0, stream>>>((const int*)ei, flag);
    convert_kernel<<<(2 * Ee + 255) / 256, 256, 0, stream>>>(ei, flag, ebuf, 2 * Ee);
    edge_stats_kernel<<<(Ee + 255) / 256, 256, 0, stream>>>(row32, col32, ea, deg, degrow,
                                                            cnt, acc + 128, Ee);
    dinv_kernel<<<(Nn + 255) / 256, 256, 0, stream>>>(deg, dinv);
    scan_kernel<<<1, 1024, 0, stream>>>(cnt, offs, Nn);
    fill_kernel<<<(Ee + 255) / 256, 256, 0, stream>>>(row32, col32, ea, dinv, offs, cursor,
                                                      cscr, cscw, cscea, Ee);
    xbf_kernel<<<(Nn * Fin / 2 + 255) / 256, 256, 0, stream>>>(x, xb, Nn * Fin / 2);
    wmfrag_kernel<<<8, 256, 0, stream>>>(Wm, (ushort16*)wfrag);

    // layer 1: xa = agg(x_bf16) [F=128], h1 = relu(xa @ W1 + b1) -> bf16
    agg128_kernel<<<(Nn + 3) / 4, 256, 0, stream>>>(xb, dinv, offs, cscr, cscw, bufA);
    dim3 ggrid((Nn + BM - 1) / BM, Hid / BN);
    gemm_bias_relu_kernel<true><<<ggrid, 256, 0, stream>>>(bufA, W1, b1, nullptr, h1b,
                                                           Nn, Fin, Hid);
    // layer 2: h1a = agg(h1_bf16) [F=256], h2 = relu(h1a @ W2 + b2) -> bf16
    agg256_kernel<<<(Nn + 3) / 4, 256, 0, stream>>>((const uint2*)h1b, dinv, offs, cscr,
                                                    cscw, bufB);
    gemm_bias_relu_kernel<true><<<ggrid, 256, 0, stream>>>(bufB, W2, b2, nullptr, h2b,
                                                           Nn, Hid, Hid);

    softmax_mfma_kernel<<<(Nn + 63) / 64, 256, 0, stream>>>((const ushort16*)h2b,
                                                            (const short8*)wfrag, bm, degrow,
                                                            out, (ushort16*)sb, acc, acc + 64);
    trace_csc_kernel<<<(Nn + 3) / 4, 256, 0, stream>>>(offs, cscr, cscea, sb, acc + 129);
    final_kernel<<<1, 1, 0, stream>>>(acc, out + (size_t)Nn * Cc);
}

// Round 5
// 234.787 us; speedup vs baseline: 1.6121x; 1.1343x over previous
//
#include <hip/hip_runtime.h>
#include <hip/hip_bf16.h>

#define Nn 10000
#define Ee 160000
#define Fin 128
#define Hid 256
#define Cc 64

typedef unsigned int uint32;
typedef unsigned short ushort16;
typedef __attribute__((ext_vector_type(8))) short short8;
typedef __attribute__((ext_vector_type(4))) float float4v;

__device__ inline float2 bfpair(uint32 u) {
    float2 r;
    r.x = __uint_as_float(u << 16);
    r.y = __uint_as_float(u & 0xffff0000u);
    return r;
}
__device__ inline ushort16 f2bf(float f) {
    __hip_bfloat16 h = __float2bfloat16(f);
    union { __hip_bfloat16 h; ushort16 u; } cv;
    cv.h = h;
    return cv.u;
}
__device__ inline uint32 packbf(float a, float b) {
    return (uint32)f2bf(a) | ((uint32)f2bf(b) << 16);
}

// ---------------- init (deg=1 self loop, zero cnt/cursor/acc) + int64 detect ----
__global__ __launch_bounds__(256) void init_detect_kernel(const int* w, int* flag,
                                                          float* deg, float* degrow,
                                                          int* cnt, int* cursor, float* acc) {
    int i = blockIdx.x * 256 + threadIdx.x;
    if (i < Nn) { deg[i] = 1.0f; degrow[i] = 0.0f; cnt[i] = 0; cursor[i] = 0; }
    if (blockIdx.x == 0 && threadIdx.x < 132) acc[threadIdx.x] = 0.0f;
    if (blockIdx.x == 1) {
        __shared__ int any;
        if (threadIdx.x == 0) any = 0;
        __syncthreads();
        for (int j = threadIdx.x; j < 1024; j += 256)
            if (w[2 * j + 1] != 0) atomicOr(&any, 1);
        __syncthreads();
        if (threadIdx.x == 0) *flag = (any == 0) ? 1 : 0;   // 1 => int64 layout
    }
}

// ---------------- fused convert + edge stats ------------------------------------
__global__ __launch_bounds__(256) void convert_stats_kernel(const void* ei, const int* flag,
                                                            const float* __restrict__ ew,
                                                            int* row32, int* col32,
                                                            float* deg, float* degrow,
                                                            int* cnt, float* g_sum_ea) {
    int e = blockIdx.x * 256 + threadIdx.x;
    float v = 0.0f;
    if (e < Ee) {
        int r, c;
        if (*flag) {
            r = (int)((const long long*)ei)[e];
            c = (int)((const long long*)ei)[Ee + e];
        } else {
            r = ((const int*)ei)[e];
            c = ((const int*)ei)[Ee + e];
        }
        row32[e] = r;
        col32[e] = c;
        float w = ew[e];
        v = w;
        atomicAdd(&deg[c], w);
        atomicAdd(&degrow[r], w);
        atomicAdd(&cnt[c], 1);
    }
    for (int off = 32; off; off >>= 1) v += __shfl_xor(v, off);
    __shared__ float sred[4];
    if ((threadIdx.x & 63) == 0) sred[threadIdx.x >> 6] = v;
    __syncthreads();
    if (threadIdx.x == 0) atomicAdd(g_sum_ea, sred[0] + sred[1] + sred[2] + sred[3]);
}

// ---------------- prep: x->bf16 + W1/W2/Wm -> MFMA B-fragment layouts -----------
// B-frag entry (KT ktiles, NT ntiles): frag[((t*NT+nt)*64+l)*8+j] =
//   bf16(W[(t*32+(l>>4)*8+j)*N + nt*16+(l&15)])
__global__ __launch_bounds__(256) void prep_kernel(const float* __restrict__ x,
                                                   const float* __restrict__ W1,
                                                   const float* __restrict__ W2,
                                                   const float* __restrict__ Wm,
                                                   uint32* __restrict__ xb,
                                                   ushort16* __restrict__ w1f,
                                                   ushort16* __restrict__ w2f,
                                                   ushort16* __restrict__ wmf) {
    int b = blockIdx.x;
    int t = threadIdx.x;
    if (b < 2500) {                                    // x: 640000 bf16 pairs
        int i = b * 256 + t;
        float2 v = *(const float2*)(x + 2 * (size_t)i);
        xb[i] = packbf(v.x, v.y);
    } else if (b < 2516) {                             // W1 frags: KT=4, NT=16
        int idx = (b - 2500) * 256 + t;
        int l = idx & 63, nt = (idx >> 6) & 15, kt = idx >> 10;
        int k0 = kt * 32 + (l >> 4) * 8, c = nt * 16 + (l & 15);
#pragma unroll
        for (int j = 0; j < 8; j++) w1f[idx * 8 + j] = f2bf(W1[(size_t)(k0 + j) * Hid + c]);
    } else if (b < 2548) {                             // W2 frags: KT=8, NT=16
        int idx = (b - 2516) * 256 + t;
        int l = idx & 63, nt = (idx >> 6) & 15, kt = idx >> 10;
        int k0 = kt * 32 + (l >> 4) * 8, c = nt * 16 + (l & 15);
#pragma unroll
        for (int j = 0; j < 8; j++) w2f[idx * 8 + j] = f2bf(W2[(size_t)(k0 + j) * Hid + c]);
    } else {                                           // Wm frags: KT=8, NT=4
        int idx = (b - 2548) * 256 + t;
        int l = idx & 63, nt = (idx >> 6) & 3, kt = idx >> 8;
        int k0 = kt * 32 + (l >> 4) * 8, c = nt * 16 + (l & 15);
#pragma unroll
        for (int j = 0; j < 8; j++) wmf[idx * 8 + j] = f2bf(Wm[(size_t)(k0 + j) * Cc + c]);
    }
}

// ---------------- single-block scan (cnt -> offs) + dinv ------------------------
__global__ __launch_bounds__(1024) void scan_dinv_kernel(const int* cnt, int* offs,
                                                         const float* deg, float* dinv, int n) {
    for (int i = threadIdx.x; i < n; i += 1024) dinv[i] = rsqrtf(deg[i]);
    __shared__ int wsum[16];
    __shared__ int carry;
    int lane = threadIdx.x & 63;
    int w = threadIdx.x >> 6;
    if (threadIdx.x == 0) { carry = 0; offs[0] = 0; }
    __syncthreads();
    for (int base = 0; base < n; base += 1024) {
        int i = base + (int)threadIdx.x;
        int v = (i < n) ? cnt[i] : 0;
        int s = v;
        for (int d = 1; d < 64; d <<= 1) {
            int t = __shfl_up(s, d);
            if (lane >= d) s += t;
        }
        if (lane == 63) wsum[w] = s;
        __syncthreads();
        if (w == 0 && lane < 16) {
            int ws = wsum[lane];
            for (int d = 1; d < 16; d <<= 1) {
                int t = __shfl_up(ws, d);
                if (lane >= d) ws += t;
            }
            wsum[lane] = ws;
        }
        __syncthreads();
        int wofs = (w > 0) ? wsum[w - 1] : 0;
        int total = wsum[15];
        if (i < n) offs[i + 1] = carry + wofs + s;
        __syncthreads();
        if (threadIdx.x == 0) carry += total;
        __syncthreads();
    }
}

// ---------------- fill CSC with (row, norm, raw ea) -----------------------------
__global__ __launch_bounds__(256) void fill_kernel(const int* __restrict__ row,
                                                   const int* __restrict__ col,
                                                   const float* __restrict__ ew,
                                                   const float* __restrict__ dinv,
                                                   const int* __restrict__ offs, int* cursor,
                                                   int* cscr, float* cscw, float* cscea,
                                                   int E) {
    int e = blockIdx.x * 256 + threadIdx.x;
    if (e >= E) return;
    int r = row[e], c = col[e];
    int slot = offs[c] + atomicAdd(&cursor[c], 1);
    float w = ew[e];
    cscr[slot] = r;
    cscw[slot] = dinv[r] * w * dinv[c];
    cscea[slot] = w;
}

// ---------------- GCN aggregation bf16 -> bf16, wave per node -------------------
__global__ __launch_bounds__(256) void agg128_kernel(const uint32* __restrict__ src,
                                                     const float* __restrict__ dinv,
                                                     const int* __restrict__ offs,
                                                     const int* __restrict__ cscr,
                                                     const float* __restrict__ cscw,
                                                     uint32* __restrict__ dst) {
    int wave = threadIdx.x >> 6, lane = threadIdx.x & 63;
    int i = blockIdx.x * 4 + wave;
    if (i >= Nn) return;
    float di = dinv[i];
    float2 self = bfpair(src[(size_t)i * 64 + lane]);
    float ax = di * di * self.x, ay = di * di * self.y;
    int e0 = offs[i], e1 = offs[i + 1];
    int k = e0;
    for (; k + 4 <= e1; k += 4) {
        int r0 = cscr[k], r1 = cscr[k + 1], r2 = cscr[k + 2], r3 = cscr[k + 3];
        float w0 = cscw[k], w1 = cscw[k + 1], w2 = cscw[k + 2], w3 = cscw[k + 3];
        uint32 u0 = src[(size_t)r0 * 64 + lane];
        uint32 u1 = src[(size_t)r1 * 64 + lane];
        uint32 u2 = src[(size_t)r2 * 64 + lane];
        uint32 u3 = src[(size_t)r3 * 64 + lane];
        float2 t0 = bfpair(u0), t1 = bfpair(u1), t2 = bfpair(u2), t3 = bfpair(u3);
        ax = fmaf(w0, t0.x, ax); ay = fmaf(w0, t0.y, ay);
        ax = fmaf(w1, t1.x, ax); ay = fmaf(w1, t1.y, ay);
        ax = fmaf(w2, t2.x, ax); ay = fmaf(w2, t2.y, ay);
        ax = fmaf(w3, t3.x, ax); ay = fmaf(w3, t3.y, ay);
    }
    for (; k < e1; k++) {
        int r0 = cscr[k];
        float w0 = cscw[k];
        float2 t0 = bfpair(src[(size_t)r0 * 64 + lane]);
        ax = fmaf(w0, t0.x, ax); ay = fmaf(w0, t0.y, ay);
    }
    dst[(size_t)i * 64 + lane] = packbf(ax, ay);
}

__global__ __launch_bounds__(256) void agg256_kernel(const uint2* __restrict__ src,
                                                     const float* __restrict__ dinv,
                                                     const int* __restrict__ offs,
                                                     const int* __restrict__ cscr,
                                                     const float* __restrict__ cscw,
                                                     uint2* __restrict__ dst) {
    int wave = threadIdx.x >> 6, lane = threadIdx.x & 63;
    int i = blockIdx.x * 4 + wave;
    if (i >= Nn) return;
    float di = dinv[i];
    uint2 su = src[(size_t)i * 64 + lane];
    float2 s0 = bfpair(su.x), s1 = bfpair(su.y);
    float a0 = di * di * s0.x, a1 = di * di * s0.y;
    float a2 = di * di * s1.x, a3 = di * di * s1.y;
    int e0 = offs[i], e1 = offs[i + 1];
    int k = e0;
    for (; k + 4 <= e1; k += 4) {
        int r0 = cscr[k], r1 = cscr[k + 1], r2 = cscr[k + 2], r3 = cscr[k + 3];
        float w0 = cscw[k], w1 = cscw[k + 1], w2 = cscw[k + 2], w3 = cscw[k + 3];
        uint2 u0 = src[(size_t)r0 * 64 + lane];
        uint2 u1 = src[(size_t)r1 * 64 + lane];
        uint2 u2 = src[(size_t)r2 * 64 + lane];
        uint2 u3 = src[(size_t)r3 * 64 + lane];
        float2 p, q;
        p = bfpair(u0.x); q = bfpair(u0.y);
        a0 = fmaf(w0, p.x, a0); a1 = fmaf(w0, p.y, a1);
        a2 = fmaf(w0, q.x, a2); a3 = fmaf(w0, q.y, a3);
        p = bfpair(u1.x); q = bfpair(u1.y);
        a0 = fmaf(w1, p.x, a0); a1 = fmaf(w1, p.y, a1);
        a2 = fmaf(w1, q.x, a2); a3 = fmaf(w1, q.y, a3);
        p = bfpair(u2.x); q = bfpair(u2.y);
        a0 = fmaf(w2, p.x, a0); a1 = fmaf(w2, p.y, a1);
        a2 = fmaf(w2, q.x, a2); a3 = fmaf(w2, q.y, a3);
        p = bfpair(u3.x); q = bfpair(u3.y);
        a0 = fmaf(w3, p.x, a0); a1 = fmaf(w3, p.y, a1);
        a2 = fmaf(w3, q.x, a2); a3 = fmaf(w3, q.y, a3);
    }
    for (; k < e1; k++) {
        int r0 = cscr[k];
        float w0 = cscw[k];
        uint2 u0 = src[(size_t)r0 * 64 + lane];
        float2 p = bfpair(u0.x), q = bfpair(u0.y);
        a0 = fmaf(w0, p.x, a0); a1 = fmaf(w0, p.y, a1);
        a2 = fmaf(w0, q.x, a2); a3 = fmaf(w0, q.y, a3);
    }
    uint2 o;
    o.x = packbf(a0, a1);
    o.y = packbf(a2, a3);
    dst[(size_t)i * 64 + lane] = o;
}

// ---------------- MFMA GEMM: C = relu(A[M,K]bf16 @ W[K,256] + b) -> bf16 --------
// wave: 16 rows x 64 cols (4 N-tiles); block: 4 waves cover 256 cols; grid 625.
// A frag: lane -> row=lane&15, k=quad*8+j. C/D: col=lane&15, row=quad*4+reg.
template <int KT>   // K = KT*32
__global__ __launch_bounds__(256) void gemm_mfma_kernel(const ushort16* __restrict__ A,
                                                        const short8* __restrict__ wfrag,
                                                        const float* __restrict__ bias,
                                                        uint32* __restrict__ Cb) {
    constexpr int K = KT * 32;
    int wave = threadIdx.x >> 6, lane = threadIdx.x & 63;
    int quad = lane >> 4, l4 = lane & 15;
    int rowbase = blockIdx.x * 16;
    int n0 = wave * 4;                      // ntile base (of 16)
    float4v acc[4];
#pragma unroll
    for (int n = 0; n < 4; n++) acc[n] = (float4v){0.f, 0.f, 0.f, 0.f};
    const short8* arow = (const short8*)(A + (size_t)(rowbase + l4) * K + quad * 8);
#pragma unroll
    for (int t = 0; t < KT; t++) {
        short8 a = arow[t * 4];
        const short8* bt = wfrag + ((size_t)t * 16 + n0) * 64 + lane;
#pragma unroll
        for (int n = 0; n < 4; n++)
            acc[n] = __builtin_amdgcn_mfma_f32_16x16x32_bf16(a, bt[n * 64], acc[n], 0, 0, 0);
    }
#pragma unroll
    for (int n = 0; n < 4; n++) {
        int col = (n0 + n) * 16 + l4;
        float bv = bias[col];
#pragma unroll
        for (int r = 0; r < 4; r++) {
            float v = fmaxf(acc[n][r] + bv, 0.0f);
            float v2 = __shfl_xor(v, 1);    // odd lane's value to even lane
            if ((l4 & 1) == 0) {
                int rowi = rowbase + quad * 4 + r;
                Cb[(size_t)rowi * 128 + (col >> 1)] = packbf(v, v2);
            }
        }
    }
}

// ---------------- MFMA softmax: logits = h2b @ Wm + bm, softmax, partials -------
__global__ __launch_bounds__(256) void softmax_mfma_kernel(const ushort16* __restrict__ h2b,
                                                           const short8* __restrict__ wfrag,
                                                           const float* __restrict__ bm,
                                                           const float* __restrict__ degrow,
                                                           float* __restrict__ s_out,
                                                           ushort16* __restrict__ s_bf,
                                                           float* __restrict__ g_clsz,
                                                           float* __restrict__ g_ca) {
    int wave = threadIdx.x >> 6, lane = threadIdx.x & 63;
    int rowbase = (blockIdx.x * 4 + wave) * 16;
    if (rowbase >= Nn) return;
    int quad = lane >> 4, l4 = lane & 15;
    float4v acc[4];
#pragma unroll
    for (int n = 0; n < 4; n++) acc[n] = (float4v){0.f, 0.f, 0.f, 0.f};
    const short8* arow = (const short8*)(h2b + (size_t)(rowbase + l4) * Hid + quad * 8);
#pragma unroll
    for (int t = 0; t < 8; t++) {
        short8 a = arow[t * 4];
        const short8* bt = wfrag + (size_t)t * 4 * 64 + lane;
#pragma unroll
        for (int n = 0; n < 4; n++) {
            acc[n] = __builtin_amdgcn_mfma_f32_16x16x32_bf16(a, bt[n * 64], acc[n], 0, 0, 0);
        }
    }
    float sv[4][4];
#pragma unroll
    for (int n = 0; n < 4; n++) {
        float bv = bm[n * 16 + l4];
#pragma unroll
        for (int r = 0; r < 4; r++) sv[n][r] = acc[n][r] + bv;
    }
#pragma unroll
    for (int r = 0; r < 4; r++) {
        float m = fmaxf(fmaxf(sv[0][r], sv[1][r]), fmaxf(sv[2][r], sv[3][r]));
        for (int o = 8; o; o >>= 1) m = fmaxf(m, __shfl_xor(m, o));
        float ssum = 0.f;
#pragma unroll
        for (int n = 0; n < 4; n++) {
            sv[n][r] = __expf(sv[n][r] - m);
            ssum += sv[n][r];
        }
        for (int o = 8; o; o >>= 1) ssum += __shfl_xor(ssum, o);
        float inv = 1.0f / ssum;
#pragma unroll
        for (int n = 0; n < 4; n++) sv[n][r] *= inv;
    }
#pragma unroll
    for (int r = 0; r < 4; r++) {
        int rowi = rowbase + quad * 4 + r;
#pragma unroll
        for (int n = 0; n < 4; n++) {
            s_out[(size_t)rowi * Cc + n * 16 + l4] = sv[n][r];
            s_bf[(size_t)rowi * Cc + n * 16 + l4] = f2bf(sv[n][r]);
        }
    }
    float dg[4];
#pragma unroll
    for (int r = 0; r < 4; r++) dg[r] = degrow[rowbase + quad * 4 + r];
#pragma unroll
    for (int n = 0; n < 4; n++) {
        float pc = sv[n][0] + sv[n][1] + sv[n][2] + sv[n][3];
        float pa = sv[n][0] * dg[0] + sv[n][1] * dg[1] + sv[n][2] * dg[2] + sv[n][3] * dg[3];
        pc += __shfl_xor(pc, 16); pc += __shfl_xor(pc, 32);
        pa += __shfl_xor(pa, 16); pa += __shfl_xor(pa, 32);
        if (quad == 0) {
            atomicAdd(&g_clsz[n * 16 + l4], pc);
            atomicAdd(&g_ca[n * 16 + l4], pa);
        }
    }
}

// ---------------- trace via CSC: wave per node, bf16 s --------------------------
__global__ __launch_bounds__(256) void trace_csc_kernel(const int* __restrict__ offs,
                                                        const int* __restrict__ cscr,
                                                        const float* __restrict__ cscea,
                                                        const uint32* __restrict__ sbf,
                                                        float* g_trace) {
    int wave = threadIdx.x >> 6, lane = threadIdx.x & 63;
    int c = blockIdx.x * 4 + wave;
    float a = 0.0f;
    if (c < Nn) {
        int l5 = lane & 31;
        int q = lane >> 5;
        float2 sc = bfpair(sbf[(size_t)c * 32 + l5]);
        int e0 = offs[c], e1 = offs[c + 1];
        int k = e0;
        for (; k + 8 <= e1; k += 8) {
            int kk = k + q;
            int r0 = cscr[kk], r1 = cscr[kk + 2], r2 = cscr[kk + 4], r3 = cscr[kk + 6];
            float w0 = cscea[kk], w1 = cscea[kk + 2], w2 = cscea[kk + 4], w3 = cscea[kk + 6];
            uint32 u0 = sbf[(size_t)r0 * 32 + l5];
            uint32 u1 = sbf[(size_t)r1 * 32 + l5];
            uint32 u2 = sbf[(size_t)r2 * 32 + l5];
            uint32 u3 = sbf[(size_t)r3 * 32 + l5];
            float2 p;
            p = bfpair(u0); a = fmaf(w0, p.x * sc.x + p.y * sc.y, a);
            p = bfpair(u1); a = fmaf(w1, p.x * sc.x + p.y * sc.y, a);
            p = bfpair(u2); a = fmaf(w2, p.x * sc.x + p.y * sc.y, a);
            p = bfpair(u3); a = fmaf(w3, p.x * sc.x + p.y * sc.y, a);
        }
        for (; k + 2 <= e1; k += 2) {
            int kk = k + q;
            int r0 = cscr[kk];
            float w0 = cscea[kk];
            float2 p = bfpair(sbf[(size_t)r0 * 32 + l5]);
            a = fmaf(w0, p.x * sc.x + p.y * sc.y, a);
        }
        if (k < e1 && q == 0) {
            int r0 = cscr[k];
            float w0 = cscea[k];
            float2 p = bfpair(sbf[(size_t)r0 * 32 + l5]);
            a = fmaf(w0, p.x * sc.x + p.y * sc.y, a);
        }
    }
    for (int o = 32; o; o >>= 1) a += __shfl_xor(a, o);
    __shared__ float sred[4];
    if (lane == 0) sred[wave] = a;
    __syncthreads();
    if (threadIdx.x == 0)
        atomicAdd(g_trace, sred[0] + sred[1] + sred[2] + sred[3]);
}

// ---------------- final scalars -------------------------------------------------
__global__ void final_kernel(const float* acc, float* out_tail) {
    float m = acc[128] * 0.5f;
    float caca = 0.0f, cc = 0.0f;
    for (int k = 0; k < Cc; k++) {
        caca += acc[64 + k] * acc[64 + k];
        cc += acc[k] * acc[k];
    }
    float tn = caca / (2.0f * m);
    float spec = -(acc[129] - tn) / (2.0f * m);
    float clust = sqrtf(cc) / (float)Nn * 8.0f - 1.0f;   // sqrt(C)=8
    out_tail[0] = 100.0f * (spec + clust);
    out_tail[1] = 100.0f * spec;
    out_tail[2] = 100.0f * clust;
}

extern "C" void kernel_launch(void* const* d_in, const int* in_sizes, int n_in,
                              void* d_out, int out_size, void* d_ws, size_t ws_size,
                              hipStream_t stream) {
    const float* x  = (const float*)d_in[0];
    const float* ea = (const float*)d_in[1];
    const float* W1 = (const float*)d_in[2];
    const float* b1 = (const float*)d_in[3];
    const float* W2 = (const float*)d_in[4];
    const float* b2 = (const float*)d_in[5];
    const float* Wm = (const float*)d_in[6];
    const float* bm = (const float*)d_in[7];
    const void*  ei = d_in[8];
    float* out = (float*)d_out;

    size_t off = 0;
    auto carve = [&](size_t bytes) -> void* {
        void* p = (char*)d_ws + off;
        off += (bytes + 255) & ~(size_t)255;
        return p;
    };
    float*  acc    = (float*)carve(132 * 4);
    int*    flag   = (int*)carve(4);
    float*  deg    = (float*)carve(Nn * 4);
    float*  dinv   = (float*)carve(Nn * 4);
    float*  degrow = (float*)carve(Nn * 4);
    int*    cnt    = (int*)carve(Nn * 4);
    int*    offs   = (int*)carve((Nn + 1) * 4);
    int*    cursor = (int*)carve(Nn * 4);
    int*    ebuf   = (int*)carve((size_t)2 * Ee * 4);
    int*    cscr   = (int*)carve(Ee * 4);
    float*  cscw   = (float*)carve(Ee * 4);
    float*  cscea  = (float*)carve(Ee * 4);
    uint32* xb     = (uint32*)carve((size_t)Nn * Fin / 2 * 4);   // x bf16
    uint32* xab    = (uint32*)carve((size_t)Nn * Fin / 2 * 4);   // agg(x) bf16
    uint32* h1b    = (uint32*)carve((size_t)Nn * Hid / 2 * 4);   // h1 bf16
    uint32* h1a    = (uint32*)carve((size_t)Nn * Hid / 2 * 4);   // agg(h1) bf16
    uint32* h2b    = (uint32*)carve((size_t)Nn * Hid / 2 * 4);   // h2 bf16
    uint32* sb     = (uint32*)carve((size_t)Nn * Cc / 2 * 4);    // s bf16
    ushort16* w1f  = (ushort16*)carve((size_t)4 * 16 * 64 * 8 * 2);
    ushort16* w2f  = (ushort16*)carve((size_t)8 * 16 * 64 * 8 * 2);
    ushort16* wmf  = (ushort16*)carve((size_t)8 * 4 * 64 * 8 * 2);
    int* row32 = ebuf;
    int* col32 = ebuf + Ee;

    init_detect_kernel<<<(Nn + 255) / 256, 256, 0, stream>>>((const int*)ei, flag, deg,
                                                             degrow, cnt, cursor, acc);
    convert_stats_kernel<<<(Ee + 255) / 256, 256, 0, stream>>>(ei, flag, ea, row32, col32,
                                                               deg, degrow, cnt, acc + 128);
    scan_dinv_kernel<<<1, 1024, 0, stream>>>(cnt, offs, deg, dinv, Nn);
    fill_kernel<<<(Ee + 255) / 256, 256, 0, stream>>>(row32, col32, ea, dinv, offs, cursor,
                                                      cscr, cscw, cscea, Ee);
    prep_kernel<<<2556, 256, 0, stream>>>(x, W1, W2, Wm, xb, w1f, w2f, wmf);

    // layer 1: xa = agg(x) bf16, h1 = relu(xa @ W1 + b1) bf16 (MFMA)
    agg128_kernel<<<(Nn + 3) / 4, 256, 0, stream>>>(xb, dinv, offs, cscr, cscw, xab);
    gemm_mfma_kernel<4><<<Nn / 16, 256, 0, stream>>>((const ushort16*)xab,
                                                     (const short8*)w1f, b1, h1b);
    // layer 2: h1a = agg(h1) bf16, h2 = relu(h1a @ W2 + b2) bf16 (MFMA)
    agg256_kernel<<<(Nn + 3) / 4, 256, 0, stream>>>((const uint2*)h1b, dinv, offs, cscr,
                                                    cscw, (uint2*)h1a);
    gemm_mfma_kernel<8><<<Nn / 16, 256, 0, stream>>>((const ushort16*)h1a,
                                                     (const short8*)w2f, b2, h2b);

    softmax_mfma_kernel<<<(Nn + 63) / 64, 256, 0, stream>>>((const ushort16*)h2b,
                                                            (const short8*)wmf, bm, degrow,
                                                            out, (ushort16*)sb, acc, acc + 64);
    trace_csc_kernel<<<(Nn + 3) / 4, 256, 0, stream>>>(offs, cscr, cscea, sb, acc + 129);
    final_kernel<<<1, 1, 0, stream>>>(acc, out + (size_t)Nn * Cc);
}

// Round 6
// 232.040 us; speedup vs baseline: 1.6312x; 1.0118x over previous
//
#include <hip/hip_runtime.h>
#include <hip/hip_bf16.h>

#define Nn 10000
#define Ee 160000
#define Fin 128
#define Hid 256
#define Cc 64

typedef unsigned int uint32;
typedef unsigned short ushort16;
typedef __attribute__((ext_vector_type(8))) short short8;
typedef __attribute__((ext_vector_type(4))) float float4v;

__device__ inline float2 bfpair(uint32 u) {
    float2 r;
    r.x = __uint_as_float(u << 16);
    r.y = __uint_as_float(u & 0xffff0000u);
    return r;
}
__device__ inline ushort16 f2bf(float f) {
    __hip_bfloat16 h = __float2bfloat16(f);
    union { __hip_bfloat16 h; ushort16 u; } cv;
    cv.h = h;
    return cv.u;
}
__device__ inline uint32 packbf(float a, float b) {
    return (uint32)f2bf(a) | ((uint32)f2bf(b) << 16);
}

// ---- fused init (deg/cnt/cursor/acc) + int64 detect + x->bf16 + W fragments ----
// blocks 0..39: init; block 0 also zeroes acc; block 1 also detects int64.
// blocks 40..2539: x->bf16. 2540..2555: W1 frags. 2556..2587: W2. 2588..2595: Wm.
__global__ __launch_bounds__(256) void initprep_kernel(const int* w, int* flag,
                                                       float* deg, float* degrow,
                                                       int* cnt, int* cursor, float* acc,
                                                       const float* __restrict__ x,
                                                       const float* __restrict__ W1,
                                                       const float* __restrict__ W2,
                                                       const float* __restrict__ Wm,
                                                       uint32* __restrict__ xb,
                                                       ushort16* __restrict__ w1f,
                                                       ushort16* __restrict__ w2f,
                                                       ushort16* __restrict__ wmf) {
    int b = blockIdx.x;
    int t = threadIdx.x;
    if (b < 40) {
        int i = b * 256 + t;
        if (i < Nn) { deg[i] = 1.0f; degrow[i] = 0.0f; cnt[i] = 0; cursor[i] = 0; }
        if (b == 0 && t < 132) acc[t] = 0.0f;
        if (b == 1) {
            __shared__ int any;
            if (t == 0) any = 0;
            __syncthreads();
            for (int j = t; j < 1024; j += 256)
                if (w[2 * j + 1] != 0) atomicOr(&any, 1);
            __syncthreads();
            if (t == 0) *flag = (any == 0) ? 1 : 0;   // 1 => int64 layout
        }
    } else if (b < 2540) {                              // x: 640000 bf16 pairs
        int i = (b - 40) * 256 + t;
        float2 v = *(const float2*)(x + 2 * (size_t)i);
        xb[i] = packbf(v.x, v.y);
    } else if (b < 2556) {                              // W1 frags: KT=4, NT=16
        int idx = (b - 2540) * 256 + t;
        int l = idx & 63, nt = (idx >> 6) & 15, kt = idx >> 10;
        int k0 = kt * 32 + (l >> 4) * 8, c = nt * 16 + (l & 15);
#pragma unroll
        for (int j = 0; j < 8; j++) w1f[idx * 8 + j] = f2bf(W1[(size_t)(k0 + j) * Hid + c]);
    } else if (b < 2588) {                              // W2 frags: KT=8, NT=16
        int idx = (b - 2556) * 256 + t;
        int l = idx & 63, nt = (idx >> 6) & 15, kt = idx >> 10;
        int k0 = kt * 32 + (l >> 4) * 8, c = nt * 16 + (l & 15);
#pragma unroll
        for (int j = 0; j < 8; j++) w2f[idx * 8 + j] = f2bf(W2[(size_t)(k0 + j) * Hid + c]);
    } else {                                            // Wm frags: KT=8, NT=4
        int idx = (b - 2588) * 256 + t;
        int l = idx & 63, nt = (idx >> 6) & 3, kt = idx >> 8;
        int k0 = kt * 32 + (l >> 4) * 8, c = nt * 16 + (l & 15);
#pragma unroll
        for (int j = 0; j < 8; j++) wmf[idx * 8 + j] = f2bf(Wm[(size_t)(k0 + j) * Cc + c]);
    }
}

// ---------------- fused convert + edge stats ------------------------------------
__global__ __launch_bounds__(256) void convert_stats_kernel(const void* ei, const int* flag,
                                                            const float* __restrict__ ew,
                                                            int* row32, int* col32,
                                                            float* deg, float* degrow,
                                                            int* cnt, float* g_sum_ea) {
    int e = blockIdx.x * 256 + threadIdx.x;
    float v = 0.0f;
    if (e < Ee) {
        int r, c;
        if (*flag) {
            r = (int)((const long long*)ei)[e];
            c = (int)((const long long*)ei)[Ee + e];
        } else {
            r = ((const int*)ei)[e];
            c = ((const int*)ei)[Ee + e];
        }
        row32[e] = r;
        col32[e] = c;
        float w = ew[e];
        v = w;
        atomicAdd(&deg[c], w);
        atomicAdd(&degrow[r], w);
        atomicAdd(&cnt[c], 1);
    }
    for (int off = 32; off; off >>= 1) v += __shfl_xor(v, off);
    __shared__ float sred[4];
    if ((threadIdx.x & 63) == 0) sred[threadIdx.x >> 6] = v;
    __syncthreads();
    if (threadIdx.x == 0) atomicAdd(g_sum_ea, sred[0] + sred[1] + sred[2] + sred[3]);
}

// ---------------- single-block scan (cnt -> offs) + dinv ------------------------
__global__ __launch_bounds__(1024) void scan_dinv_kernel(const int* cnt, int* offs,
                                                         const float* deg, float* dinv, int n) {
    for (int i = threadIdx.x; i < n; i += 1024) dinv[i] = rsqrtf(deg[i]);
    __shared__ int wsum[16];
    __shared__ int carry;
    int lane = threadIdx.x & 63;
    int w = threadIdx.x >> 6;
    if (threadIdx.x == 0) { carry = 0; offs[0] = 0; }
    __syncthreads();
    for (int base = 0; base < n; base += 1024) {
        int i = base + (int)threadIdx.x;
        int v = (i < n) ? cnt[i] : 0;
        int s = v;
        for (int d = 1; d < 64; d <<= 1) {
            int t = __shfl_up(s, d);
            if (lane >= d) s += t;
        }
        if (lane == 63) wsum[w] = s;
        __syncthreads();
        if (w == 0 && lane < 16) {
            int ws = wsum[lane];
            for (int d = 1; d < 16; d <<= 1) {
                int t = __shfl_up(ws, d);
                if (lane >= d) ws += t;
            }
            wsum[lane] = ws;
        }
        __syncthreads();
        int wofs = (w > 0) ? wsum[w - 1] : 0;
        int total = wsum[15];
        if (i < n) offs[i + 1] = carry + wofs + s;
        __syncthreads();
        if (threadIdx.x == 0) carry += total;
        __syncthreads();
    }
}

// ---------------- fill CSC with (row, norm, raw ea) -----------------------------
__global__ __launch_bounds__(256) void fill_kernel(const int* __restrict__ row,
                                                   const int* __restrict__ col,
                                                   const float* __restrict__ ew,
                                                   const float* __restrict__ dinv,
                                                   const int* __restrict__ offs, int* cursor,
                                                   int* cscr, float* cscw, float* cscea,
                                                   int E) {
    int e = blockIdx.x * 256 + threadIdx.x;
    if (e >= E) return;
    int r = row[e], c = col[e];
    int slot = offs[c] + atomicAdd(&cursor[c], 1);
    float w = ew[e];
    cscr[slot] = r;
    cscw[slot] = dinv[r] * w * dinv[c];
    cscea[slot] = w;
}

// ---------------- agg over 128-feature plane (4 B/lane rows), wave per node -----
// dst[i*DSTRIDE + lane] = packbf( di^2*src[i] + sum w_k src[r_k] )
template <int DSTRIDE>
__global__ __launch_bounds__(256) void agg_plane_kernel(const uint32* __restrict__ src,
                                                        const float* __restrict__ dinv,
                                                        const int* __restrict__ offs,
                                                        const int* __restrict__ cscr,
                                                        const float* __restrict__ cscw,
                                                        uint32* __restrict__ dst) {
    int wave = threadIdx.x >> 6, lane = threadIdx.x & 63;
    int i = blockIdx.x * 4 + wave;
    if (i >= Nn) return;
    float di = dinv[i];
    float2 self = bfpair(src[(size_t)i * 64 + lane]);
    float ax = di * di * self.x, ay = di * di * self.y;
    int e0 = offs[i], e1 = offs[i + 1];
    int k = e0;
    for (; k + 8 <= e1; k += 8) {
        int r0 = cscr[k], r1 = cscr[k + 1], r2 = cscr[k + 2], r3 = cscr[k + 3];
        int r4 = cscr[k + 4], r5 = cscr[k + 5], r6 = cscr[k + 6], r7 = cscr[k + 7];
        float w0 = cscw[k], w1 = cscw[k + 1], w2 = cscw[k + 2], w3 = cscw[k + 3];
        float w4 = cscw[k + 4], w5 = cscw[k + 5], w6 = cscw[k + 6], w7 = cscw[k + 7];
        uint32 u0 = src[(size_t)r0 * 64 + lane];
        uint32 u1 = src[(size_t)r1 * 64 + lane];
        uint32 u2 = src[(size_t)r2 * 64 + lane];
        uint32 u3 = src[(size_t)r3 * 64 + lane];
        uint32 u4 = src[(size_t)r4 * 64 + lane];
        uint32 u5 = src[(size_t)r5 * 64 + lane];
        uint32 u6 = src[(size_t)r6 * 64 + lane];
        uint32 u7 = src[(size_t)r7 * 64 + lane];
        float2 p;
        p = bfpair(u0); ax = fmaf(w0, p.x, ax); ay = fmaf(w0, p.y, ay);
        p = bfpair(u1); ax = fmaf(w1, p.x, ax); ay = fmaf(w1, p.y, ay);
        p = bfpair(u2); ax = fmaf(w2, p.x, ax); ay = fmaf(w2, p.y, ay);
        p = bfpair(u3); ax = fmaf(w3, p.x, ax); ay = fmaf(w3, p.y, ay);
        p = bfpair(u4); ax = fmaf(w4, p.x, ax); ay = fmaf(w4, p.y, ay);
        p = bfpair(u5); ax = fmaf(w5, p.x, ax); ay = fmaf(w5, p.y, ay);
        p = bfpair(u6); ax = fmaf(w6, p.x, ax); ay = fmaf(w6, p.y, ay);
        p = bfpair(u7); ax = fmaf(w7, p.x, ax); ay = fmaf(w7, p.y, ay);
    }
    if (k + 4 <= e1) {
        int r0 = cscr[k], r1 = cscr[k + 1], r2 = cscr[k + 2], r3 = cscr[k + 3];
        float w0 = cscw[k], w1 = cscw[k + 1], w2 = cscw[k + 2], w3 = cscw[k + 3];
        uint32 u0 = src[(size_t)r0 * 64 + lane];
        uint32 u1 = src[(size_t)r1 * 64 + lane];
        uint32 u2 = src[(size_t)r2 * 64 + lane];
        uint32 u3 = src[(size_t)r3 * 64 + lane];
        float2 p;
        p = bfpair(u0); ax = fmaf(w0, p.x, ax); ay = fmaf(w0, p.y, ay);
        p = bfpair(u1); ax = fmaf(w1, p.x, ax); ay = fmaf(w1, p.y, ay);
        p = bfpair(u2); ax = fmaf(w2, p.x, ax); ay = fmaf(w2, p.y, ay);
        p = bfpair(u3); ax = fmaf(w3, p.x, ax); ay = fmaf(w3, p.y, ay);
        k += 4;
    }
    for (; k < e1; k++) {
        int r0 = cscr[k];
        float w0 = cscw[k];
        float2 p = bfpair(src[(size_t)r0 * 64 + lane]);
        ax = fmaf(w0, p.x, ax); ay = fmaf(w0, p.y, ay);
    }
    dst[(size_t)i * DSTRIDE + lane] = packbf(ax, ay);
}

// ---------------- MFMA GEMM: C = relu(A[M,K]bf16 @ W[K,256] + b) -> bf16 --------
// PLANAR: write cols 0..127 to Plo, 128..255 to Phi (row stride 64 uint32 each).
// else contiguous rows of 128 uint32 via Plo.
template <int KT, bool PLANAR>
__global__ __launch_bounds__(256) void gemm_mfma_kernel(const ushort16* __restrict__ A,
                                                        const short8* __restrict__ wfrag,
                                                        const float* __restrict__ bias,
                                                        uint32* __restrict__ Plo,
                                                        uint32* __restrict__ Phi) {
    constexpr int K = KT * 32;
    int wave = threadIdx.x >> 6, lane = threadIdx.x & 63;
    int quad = lane >> 4, l4 = lane & 15;
    int rowbase = blockIdx.x * 16;
    int n0 = wave * 4;
    float4v acc[4];
#pragma unroll
    for (int n = 0; n < 4; n++) acc[n] = (float4v){0.f, 0.f, 0.f, 0.f};
    const short8* arow = (const short8*)(A + (size_t)(rowbase + l4) * K + quad * 8);
#pragma unroll
    for (int t = 0; t < KT; t++) {
        short8 a = arow[t * 4];
        const short8* bt = wfrag + ((size_t)t * 16 + n0) * 64 + lane;
#pragma unroll
        for (int n = 0; n < 4; n++)
            acc[n] = __builtin_amdgcn_mfma_f32_16x16x32_bf16(a, bt[n * 64], acc[n], 0, 0, 0);
    }
#pragma unroll
    for (int n = 0; n < 4; n++) {
        int col = (n0 + n) * 16 + l4;
        float bv = bias[col];
#pragma unroll
        for (int r = 0; r < 4; r++) {
            float v = fmaxf(acc[n][r] + bv, 0.0f);
            float v2 = __shfl_xor(v, 1);
            if ((l4 & 1) == 0) {
                int rowi = rowbase + quad * 4 + r;
                int pi = col >> 1;                       // 0..127
                uint32 val = packbf(v, v2);
                if (PLANAR) {
                    uint32* P = (pi < 64) ? Plo : Phi;
                    P[(size_t)rowi * 64 + (pi & 63)] = val;
                } else {
                    Plo[(size_t)rowi * 128 + pi] = val;
                }
            }
        }
    }
}

// ---------------- MFMA softmax: logits = h2b @ Wm + bm, softmax, partials -------
__global__ __launch_bounds__(256) void softmax_mfma_kernel(const ushort16* __restrict__ h2b,
                                                           const short8* __restrict__ wfrag,
                                                           const float* __restrict__ bm,
                                                           const float* __restrict__ degrow,
                                                           float* __restrict__ s_out,
                                                           ushort16* __restrict__ s_bf,
                                                           float* __restrict__ g_clsz,
                                                           float* __restrict__ g_ca) {
    int wave = threadIdx.x >> 6, lane = threadIdx.x & 63;
    int rowbase = (blockIdx.x * 4 + wave) * 16;
    if (rowbase >= Nn) return;
    int quad = lane >> 4, l4 = lane & 15;
    float4v acc[4];
#pragma unroll
    for (int n = 0; n < 4; n++) acc[n] = (float4v){0.f, 0.f, 0.f, 0.f};
    const short8* arow = (const short8*)(h2b + (size_t)(rowbase + l4) * Hid + quad * 8);
#pragma unroll
    for (int t = 0; t < 8; t++) {
        short8 a = arow[t * 4];
        const short8* bt = wfrag + (size_t)t * 4 * 64 + lane;
#pragma unroll
        for (int n = 0; n < 4; n++) {
            acc[n] = __builtin_amdgcn_mfma_f32_16x16x32_bf16(a, bt[n * 64], acc[n], 0, 0, 0);
        }
    }
    float sv[4][4];
#pragma unroll
    for (int n = 0; n < 4; n++) {
        float bv = bm[n * 16 + l4];
#pragma unroll
        for (int r = 0; r < 4; r++) sv[n][r] = acc[n][r] + bv;
    }
#pragma unroll
    for (int r = 0; r < 4; r++) {
        float m = fmaxf(fmaxf(sv[0][r], sv[1][r]), fmaxf(sv[2][r], sv[3][r]));
        for (int o = 8; o; o >>= 1) m = fmaxf(m, __shfl_xor(m, o));
        float ssum = 0.f;
#pragma unroll
        for (int n = 0; n < 4; n++) {
            sv[n][r] = __expf(sv[n][r] - m);
            ssum += sv[n][r];
        }
        for (int o = 8; o; o >>= 1) ssum += __shfl_xor(ssum, o);
        float inv = 1.0f / ssum;
#pragma unroll
        for (int n = 0; n < 4; n++) sv[n][r] *= inv;
    }
#pragma unroll
    for (int r = 0; r < 4; r++) {
        int rowi = rowbase + quad * 4 + r;
#pragma unroll
        for (int n = 0; n < 4; n++) {
            s_out[(size_t)rowi * Cc + n * 16 + l4] = sv[n][r];
            s_bf[(size_t)rowi * Cc + n * 16 + l4] = f2bf(sv[n][r]);
        }
    }
    float dg[4];
#pragma unroll
    for (int r = 0; r < 4; r++) dg[r] = degrow[rowbase + quad * 4 + r];
#pragma unroll
    for (int n = 0; n < 4; n++) {
        float pc = sv[n][0] + sv[n][1] + sv[n][2] + sv[n][3];
        float pa = sv[n][0] * dg[0] + sv[n][1] * dg[1] + sv[n][2] * dg[2] + sv[n][3] * dg[3];
        pc += __shfl_xor(pc, 16); pc += __shfl_xor(pc, 32);
        pa += __shfl_xor(pa, 16); pa += __shfl_xor(pa, 32);
        if (quad == 0) {
            atomicAdd(&g_clsz[n * 16 + l4], pc);
            atomicAdd(&g_ca[n * 16 + l4], pa);
        }
    }
}

// ---------------- trace via CSC: wave per node, bf16 s --------------------------
__global__ __launch_bounds__(256) void trace_csc_kernel(const int* __restrict__ offs,
                                                        const int* __restrict__ cscr,
                                                        const float* __restrict__ cscea,
                                                        const uint32* __restrict__ sbf,
                                                        float* g_trace) {
    int wave = threadIdx.x >> 6, lane = threadIdx.x & 63;
    int c = blockIdx.x * 4 + wave;
    float a = 0.0f;
    if (c < Nn) {
        int l5 = lane & 31;
        int q = lane >> 5;
        float2 sc = bfpair(sbf[(size_t)c * 32 + l5]);
        int e0 = offs[c], e1 = offs[c + 1];
        int k = e0;
        for (; k + 8 <= e1; k += 8) {
            int kk = k + q;
            int r0 = cscr[kk], r1 = cscr[kk + 2], r2 = cscr[kk + 4], r3 = cscr[kk + 6];
            float w0 = cscea[kk], w1 = cscea[kk + 2], w2 = cscea[kk + 4], w3 = cscea[kk + 6];
            uint32 u0 = sbf[(size_t)r0 * 32 + l5];
            uint32 u1 = sbf[(size_t)r1 * 32 + l5];
            uint32 u2 = sbf[(size_t)r2 * 32 + l5];
            uint32 u3 = sbf[(size_t)r3 * 32 + l5];
            float2 p;
            p = bfpair(u0); a = fmaf(w0, p.x * sc.x + p.y * sc.y, a);
            p = bfpair(u1); a = fmaf(w1, p.x * sc.x + p.y * sc.y, a);
            p = bfpair(u2); a = fmaf(w2, p.x * sc.x + p.y * sc.y, a);
            p = bfpair(u3); a = fmaf(w3, p.x * sc.x + p.y * sc.y, a);
        }
        for (; k + 2 <= e1; k += 2) {
            int kk = k + q;
            int r0 = cscr[kk];
            float w0 = cscea[kk];
            float2 p = bfpair(sbf[(size_t)r0 * 32 + l5]);
            a = fmaf(w0, p.x * sc.x + p.y * sc.y, a);
        }
        if (k < e1 && q == 0) {
            int r0 = cscr[k];
            float w0 = cscea[k];
            float2 p = bfpair(sbf[(size_t)r0 * 32 + l5]);
            a = fmaf(w0, p.x * sc.x + p.y * sc.y, a);
        }
    }
    for (int o = 32; o; o >>= 1) a += __shfl_xor(a, o);
    __shared__ float sred[4];
    if (lane == 0) sred[wave] = a;
    __syncthreads();
    if (threadIdx.x == 0)
        atomicAdd(g_trace, sred[0] + sred[1] + sred[2] + sred[3]);
}

// ---------------- final scalars -------------------------------------------------
__global__ void final_kernel(const float* acc, float* out_tail) {
    float m = acc[128] * 0.5f;
    float caca = 0.0f, cc = 0.0f;
    for (int k = 0; k < Cc; k++) {
        caca += acc[64 + k] * acc[64 + k];
        cc += acc[k] * acc[k];
    }
    float tn = caca / (2.0f * m);
    float spec = -(acc[129] - tn) / (2.0f * m);
    float clust = sqrtf(cc) / (float)Nn * 8.0f - 1.0f;   // sqrt(C)=8
    out_tail[0] = 100.0f * (spec + clust);
    out_tail[1] = 100.0f * spec;
    out_tail[2] = 100.0f * clust;
}

extern "C" void kernel_launch(void* const* d_in, const int* in_sizes, int n_in,
                              void* d_out, int out_size, void* d_ws, size_t ws_size,
                              hipStream_t stream) {
    const float* x  = (const float*)d_in[0];
    const float* ea = (const float*)d_in[1];
    const float* W1 = (const float*)d_in[2];
    const float* b1 = (const float*)d_in[3];
    const float* W2 = (const float*)d_in[4];
    const float* b2 = (const float*)d_in[5];
    const float* Wm = (const float*)d_in[6];
    const float* bm = (const float*)d_in[7];
    const void*  ei = d_in[8];
    float* out = (float*)d_out;

    size_t off = 0;
    auto carve = [&](size_t bytes) -> void* {
        void* p = (char*)d_ws + off;
        off += (bytes + 255) & ~(size_t)255;
        return p;
    };
    float*  acc    = (float*)carve(132 * 4);
    int*    flag   = (int*)carve(4);
    float*  deg    = (float*)carve(Nn * 4);
    float*  dinv   = (float*)carve(Nn * 4);
    float*  degrow = (float*)carve(Nn * 4);
    int*    cnt    = (int*)carve(Nn * 4);
    int*    offs   = (int*)carve((Nn + 1) * 4);
    int*    cursor = (int*)carve(Nn * 4);
    int*    ebuf   = (int*)carve((size_t)2 * Ee * 4);
    int*    cscr   = (int*)carve(Ee * 4);
    float*  cscw   = (float*)carve(Ee * 4);
    float*  cscea  = (float*)carve(Ee * 4);
    uint32* xb     = (uint32*)carve((size_t)Nn * 64 * 4);    // x bf16 (128f = 64 pairs)
    uint32* xab    = (uint32*)carve((size_t)Nn * 64 * 4);    // agg(x) bf16
    uint32* h1lo   = (uint32*)carve((size_t)Nn * 64 * 4);    // h1 cols 0..127 plane
    uint32* h1hi   = (uint32*)carve((size_t)Nn * 64 * 4);    // h1 cols 128..255 plane
    uint32* h1a    = (uint32*)carve((size_t)Nn * 128 * 4);   // agg(h1) bf16 contiguous
    uint32* h2b    = (uint32*)carve((size_t)Nn * 128 * 4);   // h2 bf16 contiguous
    uint32* sb     = (uint32*)carve((size_t)Nn * 32 * 4);    // s bf16
    ushort16* w1f  = (ushort16*)carve((size_t)4 * 16 * 64 * 8 * 2);
    ushort16* w2f  = (ushort16*)carve((size_t)8 * 16 * 64 * 8 * 2);
    ushort16* wmf  = (ushort16*)carve((size_t)8 * 4 * 64 * 8 * 2);
    int* row32 = ebuf;
    int* col32 = ebuf + Ee;

    initprep_kernel<<<2596, 256, 0, stream>>>((const int*)ei, flag, deg, degrow, cnt,
                                              cursor, acc, x, W1, W2, Wm, xb, w1f, w2f, wmf);
    convert_stats_kernel<<<(Ee + 255) / 256, 256, 0, stream>>>(ei, flag, ea, row32, col32,
                                                               deg, degrow, cnt, acc + 128);
    scan_dinv_kernel<<<1, 1024, 0, stream>>>(cnt, offs, deg, dinv, Nn);
    fill_kernel<<<(Ee + 255) / 256, 256, 0, stream>>>(row32, col32, ea, dinv, offs, cursor,
                                                      cscr, cscw, cscea, Ee);

    // layer 1: xa = agg(x), h1 = relu(xa @ W1 + b1) -> two 128-col planes
    agg_plane_kernel<64><<<(Nn + 3) / 4, 256, 0, stream>>>(xb, dinv, offs, cscr, cscw, xab);
    gemm_mfma_kernel<4, true><<<Nn / 16, 256, 0, stream>>>((const ushort16*)xab,
                                                           (const short8*)w1f, b1, h1lo, h1hi);
    // layer 2: h1a = agg(h1) via two L2-resident plane passes, then MFMA GEMM
    agg_plane_kernel<128><<<(Nn + 3) / 4, 256, 0, stream>>>(h1lo, dinv, offs, cscr, cscw,
                                                            h1a);
    agg_plane_kernel<128><<<(Nn + 3) / 4, 256, 0, stream>>>(h1hi, dinv, offs, cscr, cscw,
                                                            h1a + 64);
    gemm_mfma_kernel<8, false><<<Nn / 16, 256, 0, stream>>>((const ushort16*)h1a,
                                                            (const short8*)w2f, b2, h2b,
                                                            nullptr);

    softmax_mfma_kernel<<<(Nn + 63) / 64, 256, 0, stream>>>((const ushort16*)h2b,
                                                            (const short8*)wmf, bm, degrow,
                                                            out, (ushort16*)sb, acc, acc + 64);
    trace_csc_kernel<<<(Nn + 3) / 4, 256, 0, stream>>>(offs, cscr, cscea, sb, acc + 129);
    final_kernel<<<1, 1, 0, stream>>>(acc, out + (size_t)Nn * Cc);
}

// Round 8
// 205.323 us; speedup vs baseline: 1.8434x; 1.1301x over previous
//
#include <hip/hip_runtime.h>
#include <hip/hip_bf16.h>

#define Nn 10000
#define Ee 160000
#define Fin 128
#define Hid 256
#define Cc 64

typedef unsigned int uint32;
typedef unsigned short ushort16;
typedef __attribute__((ext_vector_type(8))) short short8;
typedef __attribute__((ext_vector_type(4))) float float4v;

__device__ inline float2 bfpair(uint32 u) {
    float2 r;
    r.x = __uint_as_float(u << 16);
    r.y = __uint_as_float(u & 0xffff0000u);
    return r;
}
__device__ inline ushort16 f2bf(float f) {
    __hip_bfloat16 h = __float2bfloat16(f);
    union { __hip_bfloat16 h; ushort16 u; } cv;
    cv.h = h;
    return cv.u;
}
__device__ inline uint32 packbf(float a, float b) {
    return (uint32)f2bf(a) | ((uint32)f2bf(b) << 16);
}

// ---- prep kernel: init arrays + x->bf16 + W fragments (disjoint writes only) ---
// blocks 0..39: init (b0: acc). 40..2539: x->bf16. 2540..2555: W1 frags.
// 2556..2587: W2 frags. 2588..2595: Wm frags.
__global__ __launch_bounds__(256) void prep_kernel(float* deg, float* degrow,
                                                   int* cnt, int* cursor, float* acc,
                                                   const float* __restrict__ x,
                                                   const float* __restrict__ W1,
                                                   const float* __restrict__ W2,
                                                   const float* __restrict__ Wm,
                                                   uint32* __restrict__ xb,
                                                   ushort16* __restrict__ w1f,
                                                   ushort16* __restrict__ w2f,
                                                   ushort16* __restrict__ wmf) {
    int b = blockIdx.x;
    int t = threadIdx.x;
    if (b < 40) {
        int i = b * 256 + t;
        if (i < Nn) { deg[i] = 1.0f; degrow[i] = 0.0f; cnt[i] = 0; cursor[i] = 0; }
        if (b == 0 && t < 132) acc[t] = 0.0f;
    } else if (b < 2540) {                              // x: 640000 bf16 pairs
        int i = (b - 40) * 256 + t;
        float2 v = *(const float2*)(x + 2 * (size_t)i);
        xb[i] = packbf(v.x, v.y);
    } else if (b < 2556) {                              // W1 frags: KT=4, NT=16
        int idx = (b - 2540) * 256 + t;
        int l = idx & 63, nt = (idx >> 6) & 15, kt = idx >> 10;
        int k0 = kt * 32 + (l >> 4) * 8, c = nt * 16 + (l & 15);
#pragma unroll
        for (int j = 0; j < 8; j++) w1f[idx * 8 + j] = f2bf(W1[(size_t)(k0 + j) * Hid + c]);
    } else if (b < 2588) {                              // W2 frags: KT=8, NT=16
        int idx = (b - 2556) * 256 + t;
        int l = idx & 63, nt = (idx >> 6) & 15, kt = idx >> 10;
        int k0 = kt * 32 + (l >> 4) * 8, c = nt * 16 + (l & 15);
#pragma unroll
        for (int j = 0; j < 8; j++) w2f[idx * 8 + j] = f2bf(W2[(size_t)(k0 + j) * Hid + c]);
    } else {                                            // Wm frags: KT=8, NT=4
        int idx = (b - 2588) * 256 + t;
        int l = idx & 63, nt = (idx >> 6) & 3, kt = idx >> 8;
        int k0 = kt * 32 + (l >> 4) * 8, c = nt * 16 + (l & 15);
#pragma unroll
        for (int j = 0; j < 8; j++) wmf[idx * 8 + j] = f2bf(Wm[(size_t)(k0 + j) * Cc + c]);
    }
}

// ---------------- convert + edge stats (AFTER init launch completes) ------------
// per-block int64 re-detection: values < 2^31 => all odd 32-bit words zero.
__global__ __launch_bounds__(256) void convert_stats_kernel(const void* ei,
                                                            const float* __restrict__ ew,
                                                            int* row32, int* col32,
                                                            float* deg, float* degrow,
                                                            int* cnt, float* g_sum_ea) {
    int t = threadIdx.x;
    __shared__ int any;
    if (t == 0) any = 0;
    __syncthreads();
    const int* w = (const int*)ei;
    for (int j = t; j < 1024; j += 256)
        if (w[2 * j + 1] != 0) { atomicOr(&any, 1); break; }
    __syncthreads();
    int is64 = (any == 0);
    int e = blockIdx.x * 256 + t;
    float v = 0.0f;
    if (e < Ee) {
        int r, c;
        if (is64) {
            r = (int)((const long long*)ei)[e];
            c = (int)((const long long*)ei)[Ee + e];
        } else {
            r = ((const int*)ei)[e];
            c = ((const int*)ei)[Ee + e];
        }
        row32[e] = r;
        col32[e] = c;
        float wv = ew[e];
        v = wv;
        atomicAdd(&deg[c], wv);
        atomicAdd(&degrow[r], wv);
        atomicAdd(&cnt[c], 1);
    }
    for (int o = 32; o; o >>= 1) v += __shfl_xor(v, o);
    __shared__ float sred[4];
    if ((t & 63) == 0) sred[t >> 6] = v;
    __syncthreads();
    if (t == 0) atomicAdd(g_sum_ea, sred[0] + sred[1] + sred[2] + sred[3]);
}

// ---------------- single-block scan (cnt -> offs) + dinv ------------------------
__global__ __launch_bounds__(1024) void scan_dinv_kernel(const int* cnt, int* offs,
                                                         const float* deg, float* dinv, int n) {
    for (int i = threadIdx.x; i < n; i += 1024) dinv[i] = rsqrtf(deg[i]);
    __shared__ int wsum[16];
    __shared__ int carry;
    int lane = threadIdx.x & 63;
    int w = threadIdx.x >> 6;
    if (threadIdx.x == 0) { carry = 0; offs[0] = 0; }
    __syncthreads();
    for (int base = 0; base < n; base += 1024) {
        int i = base + (int)threadIdx.x;
        int v = (i < n) ? cnt[i] : 0;
        int s = v;
        for (int d = 1; d < 64; d <<= 1) {
            int t = __shfl_up(s, d);
            if (lane >= d) s += t;
        }
        if (lane == 63) wsum[w] = s;
        __syncthreads();
        if (w == 0 && lane < 16) {
            int ws = wsum[lane];
            for (int d = 1; d < 16; d <<= 1) {
                int t = __shfl_up(ws, d);
                if (lane >= d) ws += t;
            }
            wsum[lane] = ws;
        }
        __syncthreads();
        int wofs = (w > 0) ? wsum[w - 1] : 0;
        int total = wsum[15];
        if (i < n) offs[i + 1] = carry + wofs + s;
        __syncthreads();
        if (threadIdx.x == 0) carry += total;
        __syncthreads();
    }
}

// ---------------- fill CSC as 16B records {r, norm, ea, 0} ----------------------
__global__ __launch_bounds__(256) void fill_kernel(const int* __restrict__ row,
                                                   const int* __restrict__ col,
                                                   const float* __restrict__ ew,
                                                   const float* __restrict__ dinv,
                                                   const int* __restrict__ offs, int* cursor,
                                                   uint4* __restrict__ meta, int E) {
    int e = blockIdx.x * 256 + threadIdx.x;
    if (e >= E) return;
    int r = row[e], c = col[e];
    int slot = offs[c] + atomicAdd(&cursor[c], 1);
    float w = ew[e];
    uint4 m;
    m.x = (uint32)r;
    m.y = __float_as_uint(dinv[r] * w * dinv[c]);
    m.z = __float_as_uint(w);
    m.w = 0;
    meta[slot] = m;
}

// ---------------- agg over a 128-feature plane: 16 lanes/node, uint4 gathers ----
__global__ __launch_bounds__(256) void agg16_kernel(const uint4* __restrict__ srcLo,
                                                    const uint4* __restrict__ srcHi,
                                                    const float* __restrict__ dinv,
                                                    const int* __restrict__ offs,
                                                    const uint4* __restrict__ meta,
                                                    uint4* __restrict__ dst,
                                                    int dstStride, int blocksPerPlane) {
    int b = blockIdx.x;
    int plane = (b >= blocksPerPlane) ? 1 : 0;
    const uint4* __restrict__ src = plane ? srcHi : srcLo;
    int g = threadIdx.x >> 4, l = threadIdx.x & 15;
    int i = (b - plane * blocksPerPlane) * 16 + g;
    int dof = plane * 16;
    float di = dinv[i];
    float w2 = di * di;
    uint4 su = src[(size_t)i * 16 + l];
    float a0, a1, a2, a3, a4, a5, a6, a7;
    {
        float2 p0 = bfpair(su.x), p1 = bfpair(su.y), p2 = bfpair(su.z), p3 = bfpair(su.w);
        a0 = w2 * p0.x; a1 = w2 * p0.y; a2 = w2 * p1.x; a3 = w2 * p1.y;
        a4 = w2 * p2.x; a5 = w2 * p2.y; a6 = w2 * p3.x; a7 = w2 * p3.y;
    }
#define ACC8(u, wgt) { \
        float2 p0 = bfpair(u.x), p1 = bfpair(u.y), p2 = bfpair(u.z), p3 = bfpair(u.w); \
        a0 = fmaf(wgt, p0.x, a0); a1 = fmaf(wgt, p0.y, a1); \
        a2 = fmaf(wgt, p1.x, a2); a3 = fmaf(wgt, p1.y, a3); \
        a4 = fmaf(wgt, p2.x, a4); a5 = fmaf(wgt, p2.y, a5); \
        a6 = fmaf(wgt, p3.x, a6); a7 = fmaf(wgt, p3.y, a7); }
    int e0 = offs[i], e1 = offs[i + 1];
    int k = e0;
    for (; k + 4 <= e1; k += 4) {
        uint4 m0 = meta[k], m1 = meta[k + 1], m2 = meta[k + 2], m3 = meta[k + 3];
        uint4 u0 = src[(size_t)m0.x * 16 + l];
        uint4 u1 = src[(size_t)m1.x * 16 + l];
        uint4 u2 = src[(size_t)m2.x * 16 + l];
        uint4 u3 = src[(size_t)m3.x * 16 + l];
        ACC8(u0, __uint_as_float(m0.y));
        ACC8(u1, __uint_as_float(m1.y));
        ACC8(u2, __uint_as_float(m2.y));
        ACC8(u3, __uint_as_float(m3.y));
    }
    for (; k < e1; k++) {
        uint4 m0 = meta[k];
        uint4 u0 = src[(size_t)m0.x * 16 + l];
        ACC8(u0, __uint_as_float(m0.y));
    }
#undef ACC8
    uint4 o;
    o.x = packbf(a0, a1);
    o.y = packbf(a2, a3);
    o.z = packbf(a4, a5);
    o.w = packbf(a6, a7);
    dst[(size_t)i * dstStride + dof + l] = o;
}

// ---------------- MFMA GEMM: C = relu(A[M,K]bf16 @ W[K,256] + b) -> bf16 --------
template <int KT, bool PLANAR>
__global__ __launch_bounds__(256) void gemm_mfma_kernel(const ushort16* __restrict__ A,
                                                        const short8* __restrict__ wfrag,
                                                        const float* __restrict__ bias,
                                                        uint32* __restrict__ Plo,
                                                        uint32* __restrict__ Phi) {
    constexpr int K = KT * 32;
    int wave = threadIdx.x >> 6, lane = threadIdx.x & 63;
    int quad = lane >> 4, l4 = lane & 15;
    int rowbase = blockIdx.x * 16;
    int n0 = wave * 4;
    float4v acc[4];
#pragma unroll
    for (int n = 0; n < 4; n++) acc[n] = (float4v){0.f, 0.f, 0.f, 0.f};
    const short8* arow = (const short8*)(A + (size_t)(rowbase + l4) * K + quad * 8);
#pragma unroll
    for (int t = 0; t < KT; t++) {
        short8 a = arow[t * 4];
        const short8* bt = wfrag + ((size_t)t * 16 + n0) * 64 + lane;
#pragma unroll
        for (int n = 0; n < 4; n++)
            acc[n] = __builtin_amdgcn_mfma_f32_16x16x32_bf16(a, bt[n * 64], acc[n], 0, 0, 0);
    }
#pragma unroll
    for (int n = 0; n < 4; n++) {
        int col = (n0 + n) * 16 + l4;
        float bv = bias[col];
#pragma unroll
        for (int r = 0; r < 4; r++) {
            float v = fmaxf(acc[n][r] + bv, 0.0f);
            float v2 = __shfl_xor(v, 1);
            if ((l4 & 1) == 0) {
                int rowi = rowbase + quad * 4 + r;
                int pi = col >> 1;
                uint32 val = packbf(v, v2);
                if (PLANAR) {
                    uint32* P = (pi < 64) ? Plo : Phi;
                    P[(size_t)rowi * 64 + (pi & 63)] = val;
                } else {
                    Plo[(size_t)rowi * 128 + pi] = val;
                }
            }
        }
    }
}

// ---------------- MFMA softmax: logits = h2b @ Wm + bm, softmax, partials -------
__global__ __launch_bounds__(256) void softmax_mfma_kernel(const ushort16* __restrict__ h2b,
                                                           const short8* __restrict__ wfrag,
                                                           const float* __restrict__ bm,
                                                           const float* __restrict__ degrow,
                                                           float* __restrict__ s_out,
                                                           ushort16* __restrict__ s_bf,
                                                           float* __restrict__ g_clsz,
                                                           float* __restrict__ g_ca) {
    int wave = threadIdx.x >> 6, lane = threadIdx.x & 63;
    int rowbase = (blockIdx.x * 4 + wave) * 16;
    if (rowbase >= Nn) return;
    int quad = lane >> 4, l4 = lane & 15;
    float4v acc[4];
#pragma unroll
    for (int n = 0; n < 4; n++) acc[n] = (float4v){0.f, 0.f, 0.f, 0.f};
    const short8* arow = (const short8*)(h2b + (size_t)(rowbase + l4) * Hid + quad * 8);
#pragma unroll
    for (int t = 0; t < 8; t++) {
        short8 a = arow[t * 4];
        const short8* bt = wfrag + (size_t)t * 4 * 64 + lane;
#pragma unroll
        for (int n = 0; n < 4; n++) {
            acc[n] = __builtin_amdgcn_mfma_f32_16x16x32_bf16(a, bt[n * 64], acc[n], 0, 0, 0);
        }
    }
    float sv[4][4];
#pragma unroll
    for (int n = 0; n < 4; n++) {
        float bv = bm[n * 16 + l4];
#pragma unroll
        for (int r = 0; r < 4; r++) sv[n][r] = acc[n][r] + bv;
    }
#pragma unroll
    for (int r = 0; r < 4; r++) {
        float m = fmaxf(fmaxf(sv[0][r], sv[1][r]), fmaxf(sv[2][r], sv[3][r]));
        for (int o = 8; o; o >>= 1) m = fmaxf(m, __shfl_xor(m, o));
        float ssum = 0.f;
#pragma unroll
        for (int n = 0; n < 4; n++) {
            sv[n][r] = __expf(sv[n][r] - m);
            ssum += sv[n][r];
        }
        for (int o = 8; o; o >>= 1) ssum += __shfl_xor(ssum, o);
        float inv = 1.0f / ssum;
#pragma unroll
        for (int n = 0; n < 4; n++) sv[n][r] *= inv;
    }
#pragma unroll
    for (int r = 0; r < 4; r++) {
        int rowi = rowbase + quad * 4 + r;
#pragma unroll
        for (int n = 0; n < 4; n++) {
            s_out[(size_t)rowi * Cc + n * 16 + l4] = sv[n][r];
            s_bf[(size_t)rowi * Cc + n * 16 + l4] = f2bf(sv[n][r]);
        }
    }
    float dg[4];
#pragma unroll
    for (int r = 0; r < 4; r++) dg[r] = degrow[rowbase + quad * 4 + r];
#pragma unroll
    for (int n = 0; n < 4; n++) {
        float pc = sv[n][0] + sv[n][1] + sv[n][2] + sv[n][3];
        float pa = sv[n][0] * dg[0] + sv[n][1] * dg[1] + sv[n][2] * dg[2] + sv[n][3] * dg[3];
        pc += __shfl_xor(pc, 16); pc += __shfl_xor(pc, 32);
        pa += __shfl_xor(pa, 16); pa += __shfl_xor(pa, 32);
        if (quad == 0) {
            atomicAdd(&g_clsz[n * 16 + l4], pc);
            atomicAdd(&g_ca[n * 16 + l4], pa);
        }
    }
}

// ---------------- trace via CSC: 16 lanes/col, uint2 gathers --------------------
__global__ __launch_bounds__(256) void trace16_kernel(const int* __restrict__ offs,
                                                      const uint4* __restrict__ meta,
                                                      const uint2* __restrict__ s2,
                                                      float* g_trace) {
    int g = threadIdx.x >> 4, l = threadIdx.x & 15;
    int c = blockIdx.x * 16 + g;
    uint2 sc = s2[(size_t)c * 16 + l];
    float2 c0 = bfpair(sc.x), c1 = bfpair(sc.y);
    float a = 0.0f;
    int e0 = offs[c], e1 = offs[c + 1];
    int k = e0;
    for (; k + 4 <= e1; k += 4) {
        uint4 m0 = meta[k], m1 = meta[k + 1], m2 = meta[k + 2], m3 = meta[k + 3];
        uint2 u0 = s2[(size_t)m0.x * 16 + l];
        uint2 u1 = s2[(size_t)m1.x * 16 + l];
        uint2 u2 = s2[(size_t)m2.x * 16 + l];
        uint2 u3 = s2[(size_t)m3.x * 16 + l];
        float2 p, q;
        p = bfpair(u0.x); q = bfpair(u0.y);
        a = fmaf(__uint_as_float(m0.z), p.x * c0.x + p.y * c0.y + q.x * c1.x + q.y * c1.y, a);
        p = bfpair(u1.x); q = bfpair(u1.y);
        a = fmaf(__uint_as_float(m1.z), p.x * c0.x + p.y * c0.y + q.x * c1.x + q.y * c1.y, a);
        p = bfpair(u2.x); q = bfpair(u2.y);
        a = fmaf(__uint_as_float(m2.z), p.x * c0.x + p.y * c0.y + q.x * c1.x + q.y * c1.y, a);
        p = bfpair(u3.x); q = bfpair(u3.y);
        a = fmaf(__uint_as_float(m3.z), p.x * c0.x + p.y * c0.y + q.x * c1.x + q.y * c1.y, a);
    }
    for (; k < e1; k++) {
        uint4 m0 = meta[k];
        uint2 u0 = s2[(size_t)m0.x * 16 + l];
        float2 p = bfpair(u0.x), q = bfpair(u0.y);
        a = fmaf(__uint_as_float(m0.z), p.x * c0.x + p.y * c0.y + q.x * c1.x + q.y * c1.y, a);
    }
    for (int o = 8; o; o >>= 1) a += __shfl_xor(a, o);
    __shared__ float sred[16];
    if (l == 0) sred[g] = a;
    __syncthreads();
    if (threadIdx.x == 0) {
        float s = 0.f;
#pragma unroll
        for (int j = 0; j < 16; j++) s += sred[j];
        atomicAdd(g_trace, s);
    }
}

// ---------------- final scalars -------------------------------------------------
__global__ void final_kernel(const float* acc, float* out_tail) {
    float m = acc[128] * 0.5f;
    float caca = 0.0f, cc = 0.0f;
    for (int k = 0; k < Cc; k++) {
        caca += acc[64 + k] * acc[64 + k];
        cc += acc[k] * acc[k];
    }
    float tn = caca / (2.0f * m);
    float spec = -(acc[129] - tn) / (2.0f * m);
    float clust = sqrtf(cc) / (float)Nn * 8.0f - 1.0f;   // sqrt(C)=8
    out_tail[0] = 100.0f * (spec + clust);
    out_tail[1] = 100.0f * spec;
    out_tail[2] = 100.0f * clust;
}

extern "C" void kernel_launch(void* const* d_in, const int* in_sizes, int n_in,
                              void* d_out, int out_size, void* d_ws, size_t ws_size,
                              hipStream_t stream) {
    const float* x  = (const float*)d_in[0];
    const float* ea = (const float*)d_in[1];
    const float* W1 = (const float*)d_in[2];
    const float* b1 = (const float*)d_in[3];
    const float* W2 = (const float*)d_in[4];
    const float* b2 = (const float*)d_in[5];
    const float* Wm = (const float*)d_in[6];
    const float* bm = (const float*)d_in[7];
    const void*  ei = d_in[8];
    float* out = (float*)d_out;

    size_t off = 0;
    auto carve = [&](size_t bytes) -> void* {
        void* p = (char*)d_ws + off;
        off += (bytes + 255) & ~(size_t)255;
        return p;
    };
    float*  acc    = (float*)carve(132 * 4);
    float*  deg    = (float*)carve(Nn * 4);
    float*  dinv   = (float*)carve(Nn * 4);
    float*  degrow = (float*)carve(Nn * 4);
    int*    cnt    = (int*)carve(Nn * 4);
    int*    offs   = (int*)carve((Nn + 1) * 4);
    int*    cursor = (int*)carve(Nn * 4);
    int*    ebuf   = (int*)carve((size_t)2 * Ee * 4);
    uint4*  meta   = (uint4*)carve((size_t)Ee * 16);         // {r, norm, ea, 0}
    uint32* xb     = (uint32*)carve((size_t)Nn * 64 * 4);    // x bf16
    uint32* xab    = (uint32*)carve((size_t)Nn * 64 * 4);    // agg(x) bf16
    uint32* h1lo   = (uint32*)carve((size_t)Nn * 64 * 4);    // h1 cols 0..127
    uint32* h1hi   = (uint32*)carve((size_t)Nn * 64 * 4);    // h1 cols 128..255
    uint32* h1a    = (uint32*)carve((size_t)Nn * 128 * 4);   // agg(h1) contiguous
    uint32* h2b    = (uint32*)carve((size_t)Nn * 128 * 4);   // h2 bf16
    uint32* sb     = (uint32*)carve((size_t)Nn * 32 * 4);    // s bf16
    ushort16* w1f  = (ushort16*)carve((size_t)4 * 16 * 64 * 8 * 2);
    ushort16* w2f  = (ushort16*)carve((size_t)8 * 16 * 64 * 8 * 2);
    ushort16* wmf  = (ushort16*)carve((size_t)8 * 4 * 64 * 8 * 2);
    int* row32 = ebuf;
    int* col32 = ebuf + Ee;

    prep_kernel<<<2596, 256, 0, stream>>>(deg, degrow, cnt, cursor, acc,
                                          x, W1, W2, Wm, xb, w1f, w2f, wmf);
    convert_stats_kernel<<<(Ee + 255) / 256, 256, 0, stream>>>(ei, ea, row32, col32,
                                                               deg, degrow, cnt, acc + 128);
    scan_dinv_kernel<<<1, 1024, 0, stream>>>(cnt, offs, deg, dinv, Nn);
    fill_kernel<<<(Ee + 255) / 256, 256, 0, stream>>>(row32, col32, ea, dinv, offs, cursor,
                                                      meta, Ee);

    // layer 1: xa = agg(x); h1 = relu(xa @ W1 + b1) -> two 128-col planes
    agg16_kernel<<<625, 256, 0, stream>>>((const uint4*)xb, (const uint4*)xb, dinv, offs,
                                          meta, (uint4*)xab, 16, 625);
    gemm_mfma_kernel<4, true><<<Nn / 16, 256, 0, stream>>>((const ushort16*)xab,
                                                           (const short8*)w1f, b1, h1lo, h1hi);
    // layer 2: both plane aggs in one launch; then MFMA GEMM
    agg16_kernel<<<1250, 256, 0, stream>>>((const uint4*)h1lo, (const uint4*)h1hi, dinv,
                                           offs, meta, (uint4*)h1a, 32, 625);
    gemm_mfma_kernel<8, false><<<Nn / 16, 256, 0, stream>>>((const ushort16*)h1a,
                                                            (const short8*)w2f, b2, h2b,
                                                            nullptr);

    softmax_mfma_kernel<<<(Nn + 63) / 64, 256, 0, stream>>>((const ushort16*)h2b,
                                                            (const short8*)wmf, bm, degrow,
                                                            out, (ushort16*)sb, acc, acc + 64);
    trace16_kernel<<<625, 256, 0, stream>>>(offs, meta, (const uint2*)sb, acc + 129);
    final_kernel<<<1, 1, 0, stream>>>(acc, out + (size_t)Nn * Cc);
}